// Round 9
// baseline (139.560 us; speedup 1.0000x reference)
//
#include <hip/hip_runtime.h>
#include <hip/hip_bf16.h>
#include <stdint.h>

// ---------------------------------------------------------------------------
// TrigramWriteMemoryAttention  (B=2, T=1024, D=1024, H=16, dh=64, pd=4)
// Fused buffer layout (bf16, row stride 4480):
//   cols 0:1024 Q | 1024:2048 K | 2048:3072 V (dead; V goes transposed to vtg)
//   | 3072:4096 mem_val | 4096:4480 small
// small cols (also written f32 to projf[2048][384]):
//   0:64 xw1a | 64:128 xw1b | 128:192 w2 | 192:256 r1 | 256:320 r2 | 320:336 gate
// ---------------------------------------------------------------------------

typedef __attribute__((ext_vector_type(8))) __bf16 bf16v8;
typedef __attribute__((ext_vector_type(8))) short  s16x8;
typedef __attribute__((ext_vector_type(4))) float  f32x4;

#define LOG2E 1.4426950408889634f

__device__ __forceinline__ float bf2f(short s) {
  union { uint32_t u; float f; } cv; cv.u = ((uint32_t)(uint16_t)s) << 16; return cv.f;
}
__device__ __forceinline__ short f2bf(float f) {
  union { float f; uint32_t u; } cv; cv.f = f;
  uint32_t r = cv.u + 0x7fffu + ((cv.u >> 16) & 1u);
  return (short)(r >> 16);
}

__device__ __forceinline__ f32x4 mfma_bf16(s16x8 a, s16x8 b, f32x4 c) {
  return __builtin_amdgcn_mfma_f32_16x16x32_bf16(
      __builtin_bit_cast(bf16v8, a), __builtin_bit_cast(bf16v8, b), c, 0, 0, 0);
}

__device__ __forceinline__ void gload_lds16(const void* g, void* l) {
  __builtin_amdgcn_global_load_lds(
      (const __attribute__((address_space(1))) uint32_t*)g,
      (__attribute__((address_space(3))) uint32_t*)l, 16, 0, 0);
}

// ---------------- fused prep: cvt + 3x transposed weight conv + smallw + bias

__global__ __launch_bounds__(256) void k_prep(
    const float* __restrict__ x, const float* __restrict__ qkvw,
    const float* __restrict__ mvw, const float* __restrict__ ow,
    const float* __restrict__ w1w, const float* __restrict__ w2w,
    const float* __restrict__ r1w, const float* __restrict__ r2w,
    const float* __restrict__ gw, const float* __restrict__ qkvb,
    const float* __restrict__ mvb,
    short* __restrict__ xb, short* __restrict__ btall, short* __restrict__ owT,
    float* __restrict__ biasAll) {
  __shared__ float tile[32][33];
  const int bid = blockIdx.x;
  const int tid = threadIdx.x;
  if (bid < 2048) {  // cvt
    const int i = (bid * 256 + tid) * 4;
    float4 v = *(const float4*)&x[i];
    short4 o;
    o.x = f2bf(v.x); o.y = f2bf(v.y); o.z = f2bf(v.z); o.w = f2bf(v.w);
    *(short4*)&xb[i] = o;
    return;
  }
  if (bid < 7168) {  // transposed conversions
    const float* W; short* Wt; int N, u;
    if (bid < 5120)      { W = qkvw; Wt = btall;                       N = 3072; u = bid - 2048; }
    else if (bid < 6144) { W = mvw;  Wt = btall + (size_t)3072 * 1024; N = 1024; u = bid - 5120; }
    else                 { W = ow;   Wt = owT;                         N = 1024; u = bid - 6144; }
    const int ntiles = N >> 5;
    const int n0 = (u % ntiles) * 32, k0 = (u / ntiles) * 32;
    const int tx = tid & 31, ty = tid >> 5;  // 32x8
#pragma unroll
    for (int i = 0; i < 4; i++)
      tile[ty + i * 8][tx] = W[(size_t)(k0 + ty + i * 8) * N + n0 + tx];
    __syncthreads();
#pragma unroll
    for (int i = 0; i < 4; i++)
      Wt[(size_t)(n0 + ty + i * 8) * 1024 + k0 + tx] = f2bf(tile[tx][ty + i * 8]);
    return;
  }
  if (bid < 8704) {  // small weights
    const int idx = (bid - 7168) * 256 + tid;  // 384*1024
    const int r = idx >> 10, k = idx & 1023;
    float v = 0.f;
    if (r < 64)       v = w1w[(size_t)k * 64 + r];
    else if (r < 128) v = w1w[(size_t)(1024 + k) * 64 + (r - 64)];
    else if (r < 192) v = w2w[(size_t)k * 64 + (r - 128)];
    else if (r < 256) v = r1w[(size_t)k * 64 + (r - 192)];
    else if (r < 320) v = r2w[(size_t)k * 64 + (r - 256)];
    else if (r < 336) v = gw[(size_t)k * 16 + (r - 320)];
    btall[(size_t)4096 * 1024 + idx] = f2bf(v);
    return;
  }
  {  // bias
    const int i = (bid - 8704) * 256 + tid;
    if (i < 4480) {
      float v = 0.f;
      if (i < 3072) v = qkvb[i];
      else if (i < 4096) v = mvb[i - 3072];
      biasAll[i] = v;
    }
  }
}

// ---------------- fused projection GEMM ----------------
// C[2048][4480] = xb @ btall^T + biasAll.
// proj cols (>=4096) -> projf f32; V cols [2048,3072) -> vtg TRANSPOSED
// (vtg[bh][64][1024]); others -> fusedC bf16.

__global__ __launch_bounds__(256) void k_gemmF(const short* __restrict__ A,
                                               const short* __restrict__ Bt,
                                               short* __restrict__ C,
                                               const float* __restrict__ bias,
                                               float* __restrict__ projf,
                                               short* __restrict__ vtg) {
  const int N = 4480, K = 1024;
  __shared__ short As[128 * 32];
  __shared__ short Bs[128 * 32];
  const int m0 = blockIdx.x * 128, n0 = blockIdx.y * 128;
  const int tid = threadIdx.x;
  const int lane = tid & 63, w = tid >> 6;
  const int wr = (w >> 1) * 64, wc = (w & 1) * 64;
  const int l15 = lane & 15, lg = lane >> 4;
  f32x4 acc[4][4] = {};
  for (int k0 = 0; k0 < K; k0 += 32) {
#pragma unroll
    for (int p = 0; p < 2; p++) {
      const int e = p * 256 + tid;
      const int r = e >> 2, c8 = (e & 3) << 3;
      gload_lds16(A + (size_t)(m0 + r) * K + k0 + c8, As + e * 8);
      gload_lds16(Bt + (size_t)(n0 + r) * K + k0 + c8, Bs + e * 8);
    }
    __syncthreads();
    s16x8 af[4], bfv[4];
#pragma unroll
    for (int i = 0; i < 4; i++) {
      af[i]  = *(const s16x8*)&As[(wr + i * 16 + l15) * 32 + lg * 8];
      bfv[i] = *(const s16x8*)&Bs[(wc + i * 16 + l15) * 32 + lg * 8];
    }
#pragma unroll
    for (int mi = 0; mi < 4; mi++)
#pragma unroll
      for (int ni = 0; ni < 4; ni++)
        acc[mi][ni] = mfma_bf16(af[mi], bfv[ni], acc[mi][ni]);
    __syncthreads();
  }
  const bool isproj = (n0 >= 4096);
  const bool isv = (n0 >= 2048) && (n0 < 3072);
#pragma unroll
  for (int mi = 0; mi < 4; mi++)
#pragma unroll
    for (int ni = 0; ni < 4; ni++) {
      const int col = n0 + wc + ni * 16 + l15;
      const float bv = bias[col];
      if (isv) {
        // transposed V write: 4 consecutive t -> packed short4
        const int row0 = m0 + wr + mi * 16 + lg * 4;
        const int t0 = row0 & 1023, bloc = row0 >> 10;
        const int cd = col - 2048;
        const int hh = cd >> 6, dd = cd & 63;
        short4 pk;
        pk.x = f2bf(acc[mi][ni][0] + bv);
        pk.y = f2bf(acc[mi][ni][1] + bv);
        pk.z = f2bf(acc[mi][ni][2] + bv);
        pk.w = f2bf(acc[mi][ni][3] + bv);
        *(short4*)&vtg[((size_t)((bloc << 4) + hh) * 64 + dd) * 1024 + t0] = pk;
      } else {
#pragma unroll
        for (int r = 0; r < 4; r++) {
          const int row = m0 + wr + mi * 16 + lg * 4 + r;
          const float v = acc[mi][ni][r] + bv;
          if (isproj) projf[(size_t)row * 384 + (col - 4096)] = v;
          else        C[(size_t)row * 4480 + col] = f2bf(v);
        }
      }
    }
}

// ---------------- generic GEMM (templated on BM; BN=128) ----------------

template <int BM>
__global__ __launch_bounds__(256) void k_gemm(const short* __restrict__ A,
                                              const short* __restrict__ Bt,
                                              float* __restrict__ C,
                                              const float* __restrict__ bias,
                                              int N, int K) {
  constexpr int MI = BM / 32;
  __shared__ short As[BM * 32];
  __shared__ short Bs[128 * 32];
  const int m0 = blockIdx.x * BM, n0 = blockIdx.y * 128;
  const int tid = threadIdx.x;
  const int lane = tid & 63, w = tid >> 6;
  const int wr = (w >> 1) * (BM / 2), wc = (w & 1) * 64;
  const int l15 = lane & 15, lg = lane >> 4;
  f32x4 acc[MI][4] = {};
  for (int k0 = 0; k0 < K; k0 += 32) {
    if constexpr (BM == 128) {
#pragma unroll
      for (int p = 0; p < 2; p++) {
        const int e = p * 256 + tid;
        const int r = e >> 2, c8 = (e & 3) << 3;
        gload_lds16(A + (size_t)(m0 + r) * K + k0 + c8, As + e * 8);
      }
    } else {
      const int r = tid >> 2, c8 = (tid & 3) << 3;
      gload_lds16(A + (size_t)(m0 + r) * K + k0 + c8, As + tid * 8);
    }
#pragma unroll
    for (int p = 0; p < 2; p++) {
      const int e = p * 256 + tid;
      const int r = e >> 2, c8 = (e & 3) << 3;
      gload_lds16(Bt + (size_t)(n0 + r) * K + k0 + c8, Bs + e * 8);
    }
    __syncthreads();
    s16x8 af[MI], bfv[4];
#pragma unroll
    for (int i = 0; i < MI; i++)
      af[i] = *(const s16x8*)&As[(wr + i * 16 + l15) * 32 + lg * 8];
#pragma unroll
    for (int i = 0; i < 4; i++)
      bfv[i] = *(const s16x8*)&Bs[(wc + i * 16 + l15) * 32 + lg * 8];
#pragma unroll
    for (int mi = 0; mi < MI; mi++)
#pragma unroll
      for (int ni = 0; ni < 4; ni++)
        acc[mi][ni] = mfma_bf16(af[mi], bfv[ni], acc[mi][ni]);
    __syncthreads();
  }
#pragma unroll
  for (int mi = 0; mi < MI; mi++)
#pragma unroll
    for (int ni = 0; ni < 4; ni++) {
      const int col = n0 + wc + ni * 16 + l15;
      const float bv = bias ? bias[col] : 0.f;
#pragma unroll
      for (int r = 0; r < 4; r++) {
        const int row = m0 + wr + mi * 16 + lg * 4 + r;
        C[(size_t)row * N + col] = acc[mi][ni][r] + bv;
      }
    }
}

// ---------------- flash attention, kv-split 2-way ----------------
// 1024 blocks x 4 waves: id -> j = 15-(id>>6) (LPT descending), rem = id&63,
// sid = rem>>5, bh = rem&31 (bh%8 == id%8 -> XCD-pinned heads).
// Unnormalized O + (m,l) partials to scratch; k_combine merges.

__global__ __launch_bounds__(256) void k_attn(const short* __restrict__ fused,
                                              const short* __restrict__ vtg,
                                              float* __restrict__ Of,
                                              float* __restrict__ Ml) {
  const int id = blockIdx.x;
  const int j = 15 - (id >> 6);
  const int rem = id & 63;
  const int sid = rem >> 5, bh = rem & 31;
  const int b = bh >> 4, h = bh & 15;
  const int tid = threadIdx.x, lane = tid & 63, w = tid >> 6;
  const int l15 = lane & 15, lg = lane >> 4;
  const int q0 = j * 64;
  const int nkv = j + 1;
  const int half = (nkv + 1) >> 1;
  const int lo = sid ? half : 0;
  const int hi = sid ? nkv : half;
  const int pidx = ((j * 32 + bh) << 1) | sid;

  __shared__ short Kl[64 * 72];
  __shared__ short Vt[64 * 72];        // V^T: [dh][s]
  __shared__ short Pl[4][16 * 72];     // wave-private P
  const short* base = fused + (size_t)b * 1024 * 4480;
  const short* vbase = vtg + (size_t)bh * 64 * 1024;

  const int e0 = tid, e1 = tid + 256;
  const int r0e = e0 >> 3, c0e = (e0 & 7) << 3;
  const int r1e = e1 >> 3, c1e = (e1 & 7) << 3;

  s16x8 qf[2];
#pragma unroll
  for (int ks = 0; ks < 2; ks++)
    qf[ks] = *(const s16x8*)&base[(size_t)(q0 + w * 16 + l15) * 4480 +
                                  h * 64 + ks * 32 + lg * 8];

  f32x4 O[4] = {};
  float m_run[4], l_run[4];
#pragma unroll
  for (int r = 0; r < 4; r++) { m_run[r] = -1e30f; l_run[r] = 0.f; }

  if (lo < hi) {  // stage tile lo
    const int kv0 = lo * 64;
    s16x8 ka = *(const s16x8*)&base[(size_t)(kv0 + r0e) * 4480 + 1024 + h * 64 + c0e];
    s16x8 kb = *(const s16x8*)&base[(size_t)(kv0 + r1e) * 4480 + 1024 + h * 64 + c1e];
    s16x8 va = *(const s16x8*)&vbase[(size_t)r0e * 1024 + kv0 + c0e];
    s16x8 vb = *(const s16x8*)&vbase[(size_t)r1e * 1024 + kv0 + c1e];
    *(s16x8*)&Kl[r0e * 72 + c0e] = ka;
    *(s16x8*)&Kl[r1e * 72 + c1e] = kb;
    *(s16x8*)&Vt[r0e * 72 + c0e] = va;
    *(s16x8*)&Vt[r1e * 72 + c1e] = vb;
  }
  __syncthreads();

  for (int kt = lo; kt < hi; kt++) {
    const int kv0 = kt * 64;
    const bool pf = (kt + 1 < hi);
    s16x8 kn0, kn1, vn0, vn1;
    if (pf) {
      const int kvn = kv0 + 64;
      kn0 = *(const s16x8*)&base[(size_t)(kvn + r0e) * 4480 + 1024 + h * 64 + c0e];
      kn1 = *(const s16x8*)&base[(size_t)(kvn + r1e) * 4480 + 1024 + h * 64 + c1e];
      vn0 = *(const s16x8*)&vbase[(size_t)r0e * 1024 + kvn + c0e];
      vn1 = *(const s16x8*)&vbase[(size_t)r1e * 1024 + kvn + c1e];
    }

    // S = Q @ K^T
    f32x4 S[4] = {};
    __builtin_amdgcn_s_setprio(1);
#pragma unroll
    for (int sf = 0; sf < 4; sf++) {
      s16x8 kf0 = *(const s16x8*)&Kl[(sf * 16 + l15) * 72 + lg * 8];
      s16x8 kf1 = *(const s16x8*)&Kl[(sf * 16 + l15) * 72 + 32 + lg * 8];
      S[sf] = mfma_bf16(qf[0], kf0, S[sf]);
      S[sf] = mfma_bf16(qf[1], kf1, S[sf]);
    }
    __builtin_amdgcn_s_setprio(0);

    const bool diag = (kt == j);
    float sv[4][4];
#pragma unroll
    for (int sf = 0; sf < 4; sf++)
#pragma unroll
      for (int r = 0; r < 4; r++) {
        float vv = S[sf][r] * 0.125f;
        if (diag) {
          const int sg = kv0 + sf * 16 + l15;
          const int qg = q0 + w * 16 + lg * 4 + r;
          if (sg > qg) vv = -1e30f;
        }
        sv[sf][r] = vv;
      }
#pragma unroll
    for (int r = 0; r < 4; r++) {
      float pm = fmaxf(fmaxf(sv[0][r], sv[1][r]), fmaxf(sv[2][r], sv[3][r]));
      pm = fmaxf(pm, __shfl_xor(pm, 1, 64));
      pm = fmaxf(pm, __shfl_xor(pm, 2, 64));
      pm = fmaxf(pm, __shfl_xor(pm, 4, 64));
      pm = fmaxf(pm, __shfl_xor(pm, 8, 64));
      if (pm > m_run[r] + 8.f) {  // T13 defer-max
        const float fac = exp2f((m_run[r] - pm) * LOG2E);
        m_run[r] = pm;
        l_run[r] *= fac;
#pragma unroll
        for (int nf = 0; nf < 4; nf++) O[nf][r] *= fac;
      }
      float rs = 0.f;
#pragma unroll
      for (int sf = 0; sf < 4; sf++) {
        float p = (sv[sf][r] <= -1e29f) ? 0.f : exp2f((sv[sf][r] - m_run[r]) * LOG2E);
        rs += p;
        Pl[w][(lg * 4 + r) * 72 + sf * 16 + l15] = f2bf(p);
      }
      rs += __shfl_xor(rs, 1, 64);
      rs += __shfl_xor(rs, 2, 64);
      rs += __shfl_xor(rs, 4, 64);
      rs += __shfl_xor(rs, 8, 64);
      l_run[r] += rs;
    }

    // O += P @ V
    __builtin_amdgcn_s_setprio(1);
#pragma unroll
    for (int ks = 0; ks < 2; ks++) {
      s16x8 pfr = *(const s16x8*)&Pl[w][l15 * 72 + ks * 32 + lg * 8];
#pragma unroll
      for (int nf = 0; nf < 4; nf++) {
        s16x8 vf = *(const s16x8*)&Vt[(nf * 16 + l15) * 72 + ks * 32 + lg * 8];
        O[nf] = mfma_bf16(pfr, vf, O[nf]);
      }
    }
    __builtin_amdgcn_s_setprio(0);

    __syncthreads();
    if (pf) {
      *(s16x8*)&Kl[r0e * 72 + c0e] = kn0;
      *(s16x8*)&Kl[r1e * 72 + c1e] = kn1;
      *(s16x8*)&Vt[r0e * 72 + c0e] = vn0;
      *(s16x8*)&Vt[r1e * 72 + c1e] = vn1;
      __syncthreads();
    }
  }

  // write partials (unnormalized O + m,l)
  float* ob = Of + (size_t)pidx * 4096;
  float* mb = Ml + (size_t)pidx * 128;
#pragma unroll
  for (int r = 0; r < 4; r++) {
    const int rloc = w * 16 + lg * 4 + r;
#pragma unroll
    for (int nf = 0; nf < 4; nf++)
      ob[rloc * 64 + nf * 16 + l15] = O[nf][r];
    if (l15 == 0) {
      mb[rloc] = m_run[r];
      mb[64 + rloc] = l_run[r];
    }
  }
}

// ---------------- Plucker lines ----------------

__device__ __forceinline__ void exterior6(const float p1[4], const float p2[4], float L[6]) {
  L[0] = p1[0] * p2[1] - p1[1] * p2[0];
  L[1] = p1[0] * p2[2] - p1[2] * p2[0];
  L[2] = p1[0] * p2[3] - p1[3] * p2[0];
  L[3] = p1[1] * p2[2] - p1[2] * p2[1];
  L[4] = p1[1] * p2[3] - p1[3] * p2[1];
  L[5] = p1[2] * p2[3] - p1[3] * p2[2];
  float n = sqrtf(L[0] * L[0] + L[1] * L[1] + L[2] * L[2] +
                  L[3] * L[3] + L[4] * L[4] + L[5] * L[5]);
  float inv = 1.f / fmaxf(n, 1e-12f);
#pragma unroll
  for (int j = 0; j < 6; j++) L[j] *= inv;
}

// jw layout: SoA [bh][6][1024]; rl layout: AoS [bh][t][6]
__global__ void k_lines(const float* __restrict__ proj, const float* __restrict__ Jm,
                        float* __restrict__ jw, float* __restrict__ rl) {
  const int idx = blockIdx.x * 256 + threadIdx.x;  // 32768
  const int t = idx & 1023, h = (idx >> 10) & 15, b = idx >> 14;
  const int n = b * 1024 + t;
  const int bh = b * 16 + h;
  float p1[4], p2[4], L[6];
#pragma unroll
  for (int p = 0; p < 4; p++) {
    float a  = (t >= 2) ? proj[(size_t)(n - 2) * 384 + h * 4 + p] : 0.f;
    float bb = (t >= 1) ? proj[(size_t)(n - 1) * 384 + 64 + h * 4 + p] : 0.f;
    p1[p] = a + bb;
    p2[p] = proj[(size_t)n * 384 + 128 + h * 4 + p];
  }
  exterior6(p1, p2, L);
  const size_t jo = (size_t)bh * 6144 + t;
#pragma unroll
  for (int j = 0; j < 6; j++) {
    float s = 0.f;
#pragma unroll
    for (int i = 0; i < 6; i++) s += L[i] * Jm[i * 6 + j];
    jw[jo + (size_t)j * 1024] = s;
  }
#pragma unroll
  for (int p = 0; p < 4; p++) {
    p1[p] = proj[(size_t)n * 384 + 192 + h * 4 + p];
    p2[p] = proj[(size_t)n * 384 + 256 + h * 4 + p];
  }
  exterior6(p1, p2, L);
  const size_t ro = ((size_t)bh * 1024 + t) * 6;
#pragma unroll
  for (int j = 0; j < 6; j++) rl[ro + j] = L[j];
}

// ---------------- decayed memory score ----------------

__global__ __launch_bounds__(256) void k_mscore(const float* __restrict__ jw,
                                                const float* __restrict__ rl,
                                                const float* __restrict__ dlog,
                                                float* __restrict__ ms) {
  const int gtid = blockIdx.x * 256 + threadIdx.x;
  const int wid = gtid >> 6, lane = gtid & 63;
  const int bh = wid >> 10, t = wid & 1023;
  const int h = bh & 15, b = bh >> 4;
  const float d = 1.f / (1.f + expf(-dlog[h]));
  const float l2d = log2f(d);
  const float* jwp = jw + (size_t)bh * 6144;
  const float* rp = rl + ((size_t)bh * 1024 + t) * 6;
  const float r0 = rp[0], r1 = rp[1], r2 = rp[2], r3 = rp[3], r4 = rp[4], r5 = rp[5];
  float wgt = exp2f((float)(t - lane) * l2d);
  const float gw = exp2f(-64.f * l2d);
  float acc = 0.f;
  for (int s = lane; s < t; s += 64) {
    const float dot = r0 * jwp[s] + r1 * jwp[1024 + s] + r2 * jwp[2048 + s] +
                      r3 * jwp[3072 + s] + r4 * jwp[4096 + s] + r5 * jwp[5120 + s];
    acc += wgt * dot * dot;
    wgt *= gw;
  }
  acc += __shfl_xor(acc, 1, 64);
  acc += __shfl_xor(acc, 2, 64);
  acc += __shfl_xor(acc, 4, 64);
  acc += __shfl_xor(acc, 8, 64);
  acc += __shfl_xor(acc, 16, 64);
  acc += __shfl_xor(acc, 32, 64);
  if (lane == 0) ms[((size_t)(b * 1024 + t)) * 16 + h] = acc;
}

// ---------------- combine (fused kv-split merge):
//   comb = bf16(merge(Of,Ml) + gated*mem_val)

__global__ __launch_bounds__(256) void k_combine(const float* __restrict__ Of,
                                                 const float* __restrict__ Ml,
                                                 const short* __restrict__ fused,
                                                 const float* __restrict__ proj,
                                                 const float* __restrict__ ms,
                                                 const float* __restrict__ mem_scale,
                                                 const float* __restrict__ gate_b,
                                                 short* __restrict__ comb) {
  const int n = blockIdx.x;
  const int tid = threadIdx.x;
  __shared__ float gsh;
  if (tid < 16) {
    const float gp = proj[(size_t)n * 384 + 320 + tid] + gate_b[tid];
    const float g = 1.f / (1.f + expf(-gp));
    const float sc = ms[(size_t)n * 16 + tid] * mem_scale[tid];
    const float sg = 1.f / (1.f + expf(-sc));
    float v = sg * g;
    v += __shfl_xor(v, 1, 64);
    v += __shfl_xor(v, 2, 64);
    v += __shfl_xor(v, 4, 64);
    v += __shfl_xor(v, 8, 64);
    if (tid == 0) gsh = v * (1.f / 16.f);
  }
  __syncthreads();
  const float g = gsh;
  const int b = n >> 10, t = n & 1023;
  const int c0 = tid * 4;
  const int h = c0 >> 6, coff = c0 & 63;
  const int bh = b * 16 + h;
  const int p = ((t >> 6) * 32 + bh) << 1;
  const int rloc = t & 63;
  const float m0v = Ml[(size_t)p * 128 + rloc];
  const float l0v = Ml[(size_t)p * 128 + 64 + rloc];
  const float m1v = Ml[(size_t)(p + 1) * 128 + rloc];
  const float l1v = Ml[(size_t)(p + 1) * 128 + 64 + rloc];
  const float M = fmaxf(m0v, m1v);
  const float w0 = exp2f((m0v - M) * LOG2E);
  const float w1 = exp2f((m1v - M) * LOG2E);
  const float inv = 1.f / (w0 * l0v + w1 * l1v);
  f32x4 o0 = *(const f32x4*)&Of[(size_t)p * 4096 + rloc * 64 + coff];
  f32x4 o1 = *(const f32x4*)&Of[(size_t)(p + 1) * 4096 + rloc * 64 + coff];
  short4 mvv = *(const short4*)&fused[(size_t)n * 4480 + 3072 + c0];
  short4 ov;
  ov.x = f2bf((w0 * o0[0] + w1 * o1[0]) * inv + g * bf2f(mvv.x));
  ov.y = f2bf((w0 * o0[1] + w1 * o1[1]) * inv + g * bf2f(mvv.y));
  ov.z = f2bf((w0 * o0[2] + w1 * o1[2]) * inv + g * bf2f(mvv.z));
  ov.w = f2bf((w0 * o0[3] + w1 * o1[3]) * inv + g * bf2f(mvv.w));
  *(short4*)&comb[(size_t)n * 1024 + c0] = ov;
}

// ---------------------------------------------------------------------------

extern "C" void kernel_launch(void* const* d_in, const int* in_sizes, int n_in,
                              void* d_out, int out_size, void* d_ws, size_t ws_size,
                              hipStream_t stream) {
  const float* x    = (const float*)d_in[0];
  const float* qkvw = (const float*)d_in[1];
  const float* qkvb = (const float*)d_in[2];
  const float* w1w  = (const float*)d_in[3];
  const float* w2w  = (const float*)d_in[4];
  const float* r1w  = (const float*)d_in[5];
  const float* r2w  = (const float*)d_in[6];
  const float* mvw  = (const float*)d_in[7];
  const float* mvb  = (const float*)d_in[8];
  const float* gw   = (const float*)d_in[9];
  const float* gb   = (const float*)d_in[10];
  const float* msc  = (const float*)d_in[11];
  const float* ow   = (const float*)d_in[12];
  const float* ob   = (const float*)d_in[13];
  const float* dlog = (const float*)d_in[14];
  const float* Jm   = (const float*)d_in[15];
  float* out = (float*)d_out;

  char* wsp = (char*)d_ws;
  auto alloc = [&](size_t bytes) {
    char* p = wsp;
    wsp += (bytes + 255) & ~(size_t)255;
    return p;
  };
  short* xb     = (short*)alloc((size_t)2048 * 1024 * 2);
  short* btall  = (short*)alloc((size_t)4480 * 1024 * 2);
  short* owT    = (short*)alloc((size_t)1024 * 1024 * 2);
  short* fusedC = (short*)alloc((size_t)2048 * 4480 * 2);
  float* projf  = (float*)alloc((size_t)2048 * 384 * 4);
  float* biasA  = (float*)alloc((size_t)4480 * 4);
  short* vtg    = (short*)alloc((size_t)32 * 64 * 1024 * 2);
  short* comb   = (short*)alloc((size_t)2048 * 1024 * 2);
  float* jwb    = (float*)alloc((size_t)32 * 6144 * 4);
  float* rlb    = (float*)alloc((size_t)32768 * 6 * 4);
  float* msb    = (float*)alloc((size_t)2048 * 16 * 4);
  float* Of     = (float*)alloc((size_t)1024 * 4096 * 4);
  float* Mlb    = (float*)alloc((size_t)1024 * 128 * 4);

  k_prep<<<8722, 256, 0, stream>>>(x, qkvw, mvw, ow, w1w, w2w, r1w, r2w, gw,
                                   qkvb, mvb, xb, btall, owT, biasA);

  k_gemmF<<<dim3(16, 35), 256, 0, stream>>>(xb, btall, fusedC, biasA, projf, vtg);

  k_attn<<<1024, 256, 0, stream>>>(fusedC, vtg, Of, Mlb);

  k_lines<<<128, 256, 0, stream>>>(projf, Jm, jwb, rlb);
  k_mscore<<<8192, 256, 0, stream>>>(jwb, rlb, dlog, msb);
  k_combine<<<2048, 256, 0, stream>>>(Of, Mlb, fusedC, projf, msb, msc, gb, comb);

  k_gemm<64><<<dim3(32, 8), 256, 0, stream>>>(comb, owT, out, ob, 1024, 1024);
}

// Round 10
// 126.920 us; speedup vs baseline: 1.0996x; 1.0996x over previous
//
#include <hip/hip_runtime.h>
#include <hip/hip_bf16.h>
#include <stdint.h>

// ---------------------------------------------------------------------------
// TrigramWriteMemoryAttention  (B=2, T=1024, D=1024, H=16, dh=64, pd=4)
// Fused buffer layout (bf16, row stride 4480):
//   cols 0:1024 Q | 1024:2048 K | 2048:3072 V | 3072:4096 mem_val | 4096:4480 small
// small cols (also written f32 to projf[2048][384]):
//   0:64 xw1a | 64:128 xw1b | 128:192 w2 | 192:256 r1 | 256:320 r2 | 320:336 gate
// ---------------------------------------------------------------------------

typedef __attribute__((ext_vector_type(8))) __bf16 bf16v8;
typedef __attribute__((ext_vector_type(8))) short  s16x8;
typedef __attribute__((ext_vector_type(4))) float  f32x4;

#define LOG2E 1.4426950408889634f

__device__ __forceinline__ float bf2f(short s) {
  union { uint32_t u; float f; } cv; cv.u = ((uint32_t)(uint16_t)s) << 16; return cv.f;
}
__device__ __forceinline__ short f2bf(float f) {
  union { float f; uint32_t u; } cv; cv.f = f;
  uint32_t r = cv.u + 0x7fffu + ((cv.u >> 16) & 1u);
  return (short)(r >> 16);
}

__device__ __forceinline__ f32x4 mfma_bf16(s16x8 a, s16x8 b, f32x4 c) {
  return __builtin_amdgcn_mfma_f32_16x16x32_bf16(
      __builtin_bit_cast(bf16v8, a), __builtin_bit_cast(bf16v8, b), c, 0, 0, 0);
}

__device__ __forceinline__ void gload_lds16(const void* g, void* l) {
  __builtin_amdgcn_global_load_lds(
      (const __attribute__((address_space(1))) uint32_t*)g,
      (__attribute__((address_space(3))) uint32_t*)l, 16, 0, 0);
}

// ---------------- fused prep: cvt + 3x transposed weight conv + smallw + bias

__global__ __launch_bounds__(256) void k_prep(
    const float* __restrict__ x, const float* __restrict__ qkvw,
    const float* __restrict__ mvw, const float* __restrict__ ow,
    const float* __restrict__ w1w, const float* __restrict__ w2w,
    const float* __restrict__ r1w, const float* __restrict__ r2w,
    const float* __restrict__ gw, const float* __restrict__ qkvb,
    const float* __restrict__ mvb,
    short* __restrict__ xb, short* __restrict__ btall, short* __restrict__ owT,
    float* __restrict__ biasAll) {
  __shared__ float tile[32][33];
  const int bid = blockIdx.x;
  const int tid = threadIdx.x;
  if (bid < 2048) {  // cvt
    const int i = (bid * 256 + tid) * 4;
    float4 v = *(const float4*)&x[i];
    short4 o;
    o.x = f2bf(v.x); o.y = f2bf(v.y); o.z = f2bf(v.z); o.w = f2bf(v.w);
    *(short4*)&xb[i] = o;
    return;
  }
  if (bid < 7168) {  // transposed conversions
    const float* W; short* Wt; int N, u;
    if (bid < 5120)      { W = qkvw; Wt = btall;                       N = 3072; u = bid - 2048; }
    else if (bid < 6144) { W = mvw;  Wt = btall + (size_t)3072 * 1024; N = 1024; u = bid - 5120; }
    else                 { W = ow;   Wt = owT;                         N = 1024; u = bid - 6144; }
    const int ntiles = N >> 5;
    const int n0 = (u % ntiles) * 32, k0 = (u / ntiles) * 32;
    const int tx = tid & 31, ty = tid >> 5;  // 32x8
#pragma unroll
    for (int i = 0; i < 4; i++)
      tile[ty + i * 8][tx] = W[(size_t)(k0 + ty + i * 8) * N + n0 + tx];
    __syncthreads();
#pragma unroll
    for (int i = 0; i < 4; i++)
      Wt[(size_t)(n0 + ty + i * 8) * 1024 + k0 + tx] = f2bf(tile[tx][ty + i * 8]);
    return;
  }
  if (bid < 8704) {  // small weights
    const int idx = (bid - 7168) * 256 + tid;  // 384*1024
    const int r = idx >> 10, k = idx & 1023;
    float v = 0.f;
    if (r < 64)       v = w1w[(size_t)k * 64 + r];
    else if (r < 128) v = w1w[(size_t)(1024 + k) * 64 + (r - 64)];
    else if (r < 192) v = w2w[(size_t)k * 64 + (r - 128)];
    else if (r < 256) v = r1w[(size_t)k * 64 + (r - 192)];
    else if (r < 320) v = r2w[(size_t)k * 64 + (r - 256)];
    else if (r < 336) v = gw[(size_t)k * 16 + (r - 320)];
    btall[(size_t)4096 * 1024 + idx] = f2bf(v);
    return;
  }
  {  // bias
    const int i = (bid - 8704) * 256 + tid;
    if (i < 4480) {
      float v = 0.f;
      if (i < 3072) v = qkvb[i];
      else if (i < 4096) v = mvb[i - 3072];
      biasAll[i] = v;
    }
  }
}

// ---------------- fused projection GEMM (2-phase double-buffered) ----------
// C[2048][4480] = xb @ btall^T + biasAll; proj cols (>=4096) -> projf f32.

__global__ __launch_bounds__(256) void k_gemmF(const short* __restrict__ A,
                                               const short* __restrict__ Bt,
                                               short* __restrict__ C,
                                               const float* __restrict__ bias,
                                               float* __restrict__ projf) {
  const int N = 4480, K = 1024;
  __shared__ short As[2][128 * 32];
  __shared__ short Bs[2][128 * 32];
  const int m0 = blockIdx.x * 128, n0 = blockIdx.y * 128;
  const int tid = threadIdx.x;
  const int lane = tid & 63, w = tid >> 6;
  const int wr = (w >> 1) * 64, wc = (w & 1) * 64;
  const int l15 = lane & 15, lg = lane >> 4;
  // staging coords (2 units/thread)
  const int r0e = tid >> 2, c0e = (tid & 3) << 3;
  const int r1e = (tid + 256) >> 2, c1e = ((tid + 256) & 3) << 3;
  f32x4 acc[4][4] = {};

  // prologue: stage kt=0 into buf 0
  gload_lds16(A + (size_t)(m0 + r0e) * K + c0e, &As[0][tid * 8]);
  gload_lds16(A + (size_t)(m0 + r1e) * K + c1e, &As[0][(tid + 256) * 8]);
  gload_lds16(Bt + (size_t)(n0 + r0e) * K + c0e, &Bs[0][tid * 8]);
  gload_lds16(Bt + (size_t)(n0 + r1e) * K + c1e, &Bs[0][(tid + 256) * 8]);
  __syncthreads();

  const int nkt = K >> 5;
  for (int kt = 0; kt < nkt; kt++) {
    const int cur = kt & 1;
    if (kt + 1 < nkt) {  // issue next tile's async loads into the other buffer
      const int k0n = (kt + 1) << 5;
      const int nxt = cur ^ 1;
      gload_lds16(A + (size_t)(m0 + r0e) * K + k0n + c0e, &As[nxt][tid * 8]);
      gload_lds16(A + (size_t)(m0 + r1e) * K + k0n + c1e, &As[nxt][(tid + 256) * 8]);
      gload_lds16(Bt + (size_t)(n0 + r0e) * K + k0n + c0e, &Bs[nxt][tid * 8]);
      gload_lds16(Bt + (size_t)(n0 + r1e) * K + k0n + c1e, &Bs[nxt][(tid + 256) * 8]);
    }
    s16x8 af[4], bfv[4];
#pragma unroll
    for (int i = 0; i < 4; i++) {
      af[i]  = *(const s16x8*)&As[cur][(wr + i * 16 + l15) * 32 + lg * 8];
      bfv[i] = *(const s16x8*)&Bs[cur][(wc + i * 16 + l15) * 32 + lg * 8];
    }
    __builtin_amdgcn_s_setprio(1);
#pragma unroll
    for (int mi = 0; mi < 4; mi++)
#pragma unroll
      for (int ni = 0; ni < 4; ni++)
        acc[mi][ni] = mfma_bf16(af[mi], bfv[ni], acc[mi][ni]);
    __builtin_amdgcn_s_setprio(0);
    __syncthreads();  // drains prefetch (it has had the whole compute phase)
  }
  const bool isproj = (n0 >= 4096);
#pragma unroll
  for (int mi = 0; mi < 4; mi++)
#pragma unroll
    for (int ni = 0; ni < 4; ni++) {
      const int col = n0 + wc + ni * 16 + l15;
      const float bv = bias[col];
#pragma unroll
      for (int r = 0; r < 4; r++) {
        const int row = m0 + wr + mi * 16 + lg * 4 + r;
        const float v = acc[mi][ni][r] + bv;
        if (isproj) projf[(size_t)row * 384 + (col - 4096)] = v;
        else        C[(size_t)row * 4480 + col] = f2bf(v);
      }
    }
}

// ---------------- generic GEMM (templated BM; BN=128; 2-phase dbuf) --------

template <int BM>
__global__ __launch_bounds__(256) void k_gemm(const short* __restrict__ A,
                                              const short* __restrict__ Bt,
                                              float* __restrict__ C,
                                              const float* __restrict__ bias,
                                              int N, int K) {
  constexpr int MI = BM / 32;
  __shared__ short As[2][BM * 32];
  __shared__ short Bs[2][128 * 32];
  const int m0 = blockIdx.x * BM, n0 = blockIdx.y * 128;
  const int tid = threadIdx.x;
  const int lane = tid & 63, w = tid >> 6;
  const int wr = (w >> 1) * (BM / 2), wc = (w & 1) * 64;
  const int l15 = lane & 15, lg = lane >> 4;
  const int r0e = tid >> 2, c0e = (tid & 3) << 3;
  const int r1e = (tid + 256) >> 2, c1e = ((tid + 256) & 3) << 3;
  f32x4 acc[MI][4] = {};

  auto stage = [&](int buf, int k0) {
    if constexpr (BM == 128) {
      gload_lds16(A + (size_t)(m0 + r0e) * K + k0 + c0e, &As[buf][tid * 8]);
      gload_lds16(A + (size_t)(m0 + r1e) * K + k0 + c1e, &As[buf][(tid + 256) * 8]);
    } else {
      gload_lds16(A + (size_t)(m0 + r0e) * K + k0 + c0e, &As[buf][tid * 8]);
    }
    gload_lds16(Bt + (size_t)(n0 + r0e) * K + k0 + c0e, &Bs[buf][tid * 8]);
    gload_lds16(Bt + (size_t)(n0 + r1e) * K + k0 + c1e, &Bs[buf][(tid + 256) * 8]);
  };

  stage(0, 0);
  __syncthreads();
  const int nkt = K >> 5;
  for (int kt = 0; kt < nkt; kt++) {
    const int cur = kt & 1;
    if (kt + 1 < nkt) stage(cur ^ 1, (kt + 1) << 5);
    s16x8 af[MI], bfv[4];
#pragma unroll
    for (int i = 0; i < MI; i++)
      af[i] = *(const s16x8*)&As[cur][(wr + i * 16 + l15) * 32 + lg * 8];
#pragma unroll
    for (int i = 0; i < 4; i++)
      bfv[i] = *(const s16x8*)&Bs[cur][(wc + i * 16 + l15) * 32 + lg * 8];
    __builtin_amdgcn_s_setprio(1);
#pragma unroll
    for (int mi = 0; mi < MI; mi++)
#pragma unroll
      for (int ni = 0; ni < 4; ni++)
        acc[mi][ni] = mfma_bf16(af[mi], bfv[ni], acc[mi][ni]);
    __builtin_amdgcn_s_setprio(0);
    __syncthreads();
  }
#pragma unroll
  for (int mi = 0; mi < MI; mi++)
#pragma unroll
    for (int ni = 0; ni < 4; ni++) {
      const int col = n0 + wc + ni * 16 + l15;
      const float bv = bias ? bias[col] : 0.f;
#pragma unroll
      for (int r = 0; r < 4; r++) {
        const int row = m0 + wr + mi * 16 + lg * 4 + r;
        C[(size_t)row * N + col] = acc[mi][ni][r] + bv;
      }
    }
}

// ---------------- V transpose: fused V cols -> vtg[bh][64][1024] ------------

__global__ void k_vtr(const short* __restrict__ fused, short* __restrict__ vtg) {
  __shared__ short tile[32][33];
  const int bh = blockIdx.z;
  const int b = bh >> 4, h = bh & 15;
  const int t0 = blockIdx.x * 32, d0 = blockIdx.y * 32;
  const int tx = threadIdx.x, ty = threadIdx.y;  // 32x8
#pragma unroll
  for (int i = 0; i < 4; i++)
    tile[ty + i * 8][tx] =
        fused[(size_t)(b * 1024 + t0 + ty + i * 8) * 4480 + 2048 + h * 64 + d0 + tx];
  __syncthreads();
#pragma unroll
  for (int i = 0; i < 4; i++)
    vtg[(size_t)(bh * 64 + d0 + ty + i * 8) * 1024 + t0 + tx] = tile[tx][ty + i * 8];
}

// ---------------- flash attention, kv-split 2-way ----------------

__global__ __launch_bounds__(256) void k_attn(const short* __restrict__ fused,
                                              const short* __restrict__ vtg,
                                              float* __restrict__ Of,
                                              float* __restrict__ Ml) {
  const int id = blockIdx.x;
  const int j = 15 - (id >> 6);
  const int rem = id & 63;
  const int sid = rem >> 5, bh = rem & 31;
  const int b = bh >> 4, h = bh & 15;
  const int tid = threadIdx.x, lane = tid & 63, w = tid >> 6;
  const int l15 = lane & 15, lg = lane >> 4;
  const int q0 = j * 64;
  const int nkv = j + 1;
  const int half = (nkv + 1) >> 1;
  const int lo = sid ? half : 0;
  const int hi = sid ? nkv : half;
  const int pidx = ((j * 32 + bh) << 1) | sid;

  __shared__ short Kl[64 * 72];
  __shared__ short Vt[64 * 72];
  __shared__ short Pl[4][16 * 72];
  const short* base = fused + (size_t)b * 1024 * 4480;
  const short* vbase = vtg + (size_t)bh * 64 * 1024;

  const int e0 = tid, e1 = tid + 256;
  const int r0e = e0 >> 3, c0e = (e0 & 7) << 3;
  const int r1e = e1 >> 3, c1e = (e1 & 7) << 3;

  s16x8 qf[2];
#pragma unroll
  for (int ks = 0; ks < 2; ks++)
    qf[ks] = *(const s16x8*)&base[(size_t)(q0 + w * 16 + l15) * 4480 +
                                  h * 64 + ks * 32 + lg * 8];

  f32x4 O[4] = {};
  float m_run[4], l_run[4];
#pragma unroll
  for (int r = 0; r < 4; r++) { m_run[r] = -1e30f; l_run[r] = 0.f; }

  if (lo < hi) {
    const int kv0 = lo * 64;
    s16x8 ka = *(const s16x8*)&base[(size_t)(kv0 + r0e) * 4480 + 1024 + h * 64 + c0e];
    s16x8 kb = *(const s16x8*)&base[(size_t)(kv0 + r1e) * 4480 + 1024 + h * 64 + c1e];
    s16x8 va = *(const s16x8*)&vbase[(size_t)r0e * 1024 + kv0 + c0e];
    s16x8 vb = *(const s16x8*)&vbase[(size_t)r1e * 1024 + kv0 + c1e];
    *(s16x8*)&Kl[r0e * 72 + c0e] = ka;
    *(s16x8*)&Kl[r1e * 72 + c1e] = kb;
    *(s16x8*)&Vt[r0e * 72 + c0e] = va;
    *(s16x8*)&Vt[r1e * 72 + c1e] = vb;
  }
  __syncthreads();

  for (int kt = lo; kt < hi; kt++) {
    const int kv0 = kt * 64;
    const bool pf = (kt + 1 < hi);
    s16x8 kn0, kn1, vn0, vn1;
    if (pf) {
      const int kvn = kv0 + 64;
      kn0 = *(const s16x8*)&base[(size_t)(kvn + r0e) * 4480 + 1024 + h * 64 + c0e];
      kn1 = *(const s16x8*)&base[(size_t)(kvn + r1e) * 4480 + 1024 + h * 64 + c1e];
      vn0 = *(const s16x8*)&vbase[(size_t)r0e * 1024 + kvn + c0e];
      vn1 = *(const s16x8*)&vbase[(size_t)r1e * 1024 + kvn + c1e];
    }

    // S = Q @ K^T
    f32x4 S[4] = {};
    __builtin_amdgcn_s_setprio(1);
#pragma unroll
    for (int sf = 0; sf < 4; sf++) {
      s16x8 kf0 = *(const s16x8*)&Kl[(sf * 16 + l15) * 72 + lg * 8];
      s16x8 kf1 = *(const s16x8*)&Kl[(sf * 16 + l15) * 72 + 32 + lg * 8];
      S[sf] = mfma_bf16(qf[0], kf0, S[sf]);
      S[sf] = mfma_bf16(qf[1], kf1, S[sf]);
    }
    __builtin_amdgcn_s_setprio(0);

    const bool diag = (kt == j);
    float sv[4][4];
#pragma unroll
    for (int sf = 0; sf < 4; sf++)
#pragma unroll
      for (int r = 0; r < 4; r++) {
        float vv = S[sf][r] * 0.125f;
        if (diag) {
          const int sg = kv0 + sf * 16 + l15;
          const int qg = q0 + w * 16 + lg * 4 + r;
          if (sg > qg) vv = -1e30f;
        }
        sv[sf][r] = vv;
      }
#pragma unroll
    for (int r = 0; r < 4; r++) {
      float pm = fmaxf(fmaxf(sv[0][r], sv[1][r]), fmaxf(sv[2][r], sv[3][r]));
      pm = fmaxf(pm, __shfl_xor(pm, 1, 64));
      pm = fmaxf(pm, __shfl_xor(pm, 2, 64));
      pm = fmaxf(pm, __shfl_xor(pm, 4, 64));
      pm = fmaxf(pm, __shfl_xor(pm, 8, 64));
      if (pm > m_run[r] + 8.f) {  // T13 defer-max
        const float fac = exp2f((m_run[r] - pm) * LOG2E);
        m_run[r] = pm;
        l_run[r] *= fac;
#pragma unroll
        for (int nf = 0; nf < 4; nf++) O[nf][r] *= fac;
      }
      float rs = 0.f;
#pragma unroll
      for (int sf = 0; sf < 4; sf++) {
        float p = (sv[sf][r] <= -1e29f) ? 0.f : exp2f((sv[sf][r] - m_run[r]) * LOG2E);
        rs += p;
        Pl[w][(lg * 4 + r) * 72 + sf * 16 + l15] = f2bf(p);
      }
      rs += __shfl_xor(rs, 1, 64);
      rs += __shfl_xor(rs, 2, 64);
      rs += __shfl_xor(rs, 4, 64);
      rs += __shfl_xor(rs, 8, 64);
      l_run[r] += rs;
    }

    // O += P @ V
    __builtin_amdgcn_s_setprio(1);
#pragma unroll
    for (int ks = 0; ks < 2; ks++) {
      s16x8 pfr = *(const s16x8*)&Pl[w][l15 * 72 + ks * 32 + lg * 8];
#pragma unroll
      for (int nf = 0; nf < 4; nf++) {
        s16x8 vf = *(const s16x8*)&Vt[(nf * 16 + l15) * 72 + ks * 32 + lg * 8];
        O[nf] = mfma_bf16(pfr, vf, O[nf]);
      }
    }
    __builtin_amdgcn_s_setprio(0);

    __syncthreads();
    if (pf) {
      *(s16x8*)&Kl[r0e * 72 + c0e] = kn0;
      *(s16x8*)&Kl[r1e * 72 + c1e] = kn1;
      *(s16x8*)&Vt[r0e * 72 + c0e] = vn0;
      *(s16x8*)&Vt[r1e * 72 + c1e] = vn1;
      __syncthreads();
    }
  }

  float* ob = Of + (size_t)pidx * 4096;
  float* mb = Ml + (size_t)pidx * 128;
#pragma unroll
  for (int r = 0; r < 4; r++) {
    const int rloc = w * 16 + lg * 4 + r;
#pragma unroll
    for (int nf = 0; nf < 4; nf++)
      ob[rloc * 64 + nf * 16 + l15] = O[nf][r];
    if (l15 == 0) {
      mb[rloc] = m_run[r];
      mb[64 + rloc] = l_run[r];
    }
  }
}

// ---------------- Plucker lines ----------------

__device__ __forceinline__ void exterior6(const float p1[4], const float p2[4], float L[6]) {
  L[0] = p1[0] * p2[1] - p1[1] * p2[0];
  L[1] = p1[0] * p2[2] - p1[2] * p2[0];
  L[2] = p1[0] * p2[3] - p1[3] * p2[0];
  L[3] = p1[1] * p2[2] - p1[2] * p2[1];
  L[4] = p1[1] * p2[3] - p1[3] * p2[1];
  L[5] = p1[2] * p2[3] - p1[3] * p2[2];
  float n = sqrtf(L[0] * L[0] + L[1] * L[1] + L[2] * L[2] +
                  L[3] * L[3] + L[4] * L[4] + L[5] * L[5]);
  float inv = 1.f / fmaxf(n, 1e-12f);
#pragma unroll
  for (int j = 0; j < 6; j++) L[j] *= inv;
}

// jw layout: SoA [bh][6][1024]; rl layout: AoS [bh][t][6]
__global__ void k_lines(const float* __restrict__ proj, const float* __restrict__ Jm,
                        float* __restrict__ jw, float* __restrict__ rl) {
  const int idx = blockIdx.x * 256 + threadIdx.x;  // 32768
  const int t = idx & 1023, h = (idx >> 10) & 15, b = idx >> 14;
  const int n = b * 1024 + t;
  const int bh = b * 16 + h;
  float p1[4], p2[4], L[6];
#pragma unroll
  for (int p = 0; p < 4; p++) {
    float a  = (t >= 2) ? proj[(size_t)(n - 2) * 384 + h * 4 + p] : 0.f;
    float bb = (t >= 1) ? proj[(size_t)(n - 1) * 384 + 64 + h * 4 + p] : 0.f;
    p1[p] = a + bb;
    p2[p] = proj[(size_t)n * 384 + 128 + h * 4 + p];
  }
  exterior6(p1, p2, L);
  const size_t jo = (size_t)bh * 6144 + t;
#pragma unroll
  for (int j = 0; j < 6; j++) {
    float s = 0.f;
#pragma unroll
    for (int i = 0; i < 6; i++) s += L[i] * Jm[i * 6 + j];
    jw[jo + (size_t)j * 1024] = s;
  }
#pragma unroll
  for (int p = 0; p < 4; p++) {
    p1[p] = proj[(size_t)n * 384 + 192 + h * 4 + p];
    p2[p] = proj[(size_t)n * 384 + 256 + h * 4 + p];
  }
  exterior6(p1, p2, L);
  const size_t ro = ((size_t)bh * 1024 + t) * 6;
#pragma unroll
  for (int j = 0; j < 6; j++) rl[ro + j] = L[j];
}

// ---------------- decayed memory score ----------------

__global__ __launch_bounds__(256) void k_mscore(const float* __restrict__ jw,
                                                const float* __restrict__ rl,
                                                const float* __restrict__ dlog,
                                                float* __restrict__ ms) {
  const int gtid = blockIdx.x * 256 + threadIdx.x;
  const int wid = gtid >> 6, lane = gtid & 63;
  const int bh = wid >> 10, t = wid & 1023;
  const int h = bh & 15, b = bh >> 4;
  const float d = 1.f / (1.f + expf(-dlog[h]));
  const float l2d = log2f(d);
  const float* jwp = jw + (size_t)bh * 6144;
  const float* rp = rl + ((size_t)bh * 1024 + t) * 6;
  const float r0 = rp[0], r1 = rp[1], r2 = rp[2], r3 = rp[3], r4 = rp[4], r5 = rp[5];
  float wgt = exp2f((float)(t - lane) * l2d);
  const float gw = exp2f(-64.f * l2d);
  float acc = 0.f;
  for (int s = lane; s < t; s += 64) {
    const float dot = r0 * jwp[s] + r1 * jwp[1024 + s] + r2 * jwp[2048 + s] +
                      r3 * jwp[3072 + s] + r4 * jwp[4096 + s] + r5 * jwp[5120 + s];
    acc += wgt * dot * dot;
    wgt *= gw;
  }
  acc += __shfl_xor(acc, 1, 64);
  acc += __shfl_xor(acc, 2, 64);
  acc += __shfl_xor(acc, 4, 64);
  acc += __shfl_xor(acc, 8, 64);
  acc += __shfl_xor(acc, 16, 64);
  acc += __shfl_xor(acc, 32, 64);
  if (lane == 0) ms[((size_t)(b * 1024 + t)) * 16 + h] = acc;
}

// ---------------- combine (fused kv-split merge) ----------------

__global__ __launch_bounds__(256) void k_combine(const float* __restrict__ Of,
                                                 const float* __restrict__ Ml,
                                                 const short* __restrict__ fused,
                                                 const float* __restrict__ proj,
                                                 const float* __restrict__ ms,
                                                 const float* __restrict__ mem_scale,
                                                 const float* __restrict__ gate_b,
                                                 short* __restrict__ comb) {
  const int n = blockIdx.x;
  const int tid = threadIdx.x;
  __shared__ float gsh;
  if (tid < 16) {
    const float gp = proj[(size_t)n * 384 + 320 + tid] + gate_b[tid];
    const float g = 1.f / (1.f + expf(-gp));
    const float sc = ms[(size_t)n * 16 + tid] * mem_scale[tid];
    const float sg = 1.f / (1.f + expf(-sc));
    float v = sg * g;
    v += __shfl_xor(v, 1, 64);
    v += __shfl_xor(v, 2, 64);
    v += __shfl_xor(v, 4, 64);
    v += __shfl_xor(v, 8, 64);
    if (tid == 0) gsh = v * (1.f / 16.f);
  }
  __syncthreads();
  const float g = gsh;
  const int b = n >> 10, t = n & 1023;
  const int c0 = tid * 4;
  const int h = c0 >> 6, coff = c0 & 63;
  const int bh = b * 16 + h;
  const int p = ((t >> 6) * 32 + bh) << 1;
  const int rloc = t & 63;
  const float m0v = Ml[(size_t)p * 128 + rloc];
  const float l0v = Ml[(size_t)p * 128 + 64 + rloc];
  const float m1v = Ml[(size_t)(p + 1) * 128 + rloc];
  const float l1v = Ml[(size_t)(p + 1) * 128 + 64 + rloc];
  const float M = fmaxf(m0v, m1v);
  const float w0 = exp2f((m0v - M) * LOG2E);
  const float w1 = exp2f((m1v - M) * LOG2E);
  const float inv = 1.f / (w0 * l0v + w1 * l1v);
  f32x4 o0 = *(const f32x4*)&Of[(size_t)p * 4096 + rloc * 64 + coff];
  f32x4 o1 = *(const f32x4*)&Of[(size_t)(p + 1) * 4096 + rloc * 64 + coff];
  short4 mvv = *(const short4*)&fused[(size_t)n * 4480 + 3072 + c0];
  short4 ov;
  ov.x = f2bf((w0 * o0[0] + w1 * o1[0]) * inv + g * bf2f(mvv.x));
  ov.y = f2bf((w0 * o0[1] + w1 * o1[1]) * inv + g * bf2f(mvv.y));
  ov.z = f2bf((w0 * o0[2] + w1 * o1[2]) * inv + g * bf2f(mvv.z));
  ov.w = f2bf((w0 * o0[3] + w1 * o1[3]) * inv + g * bf2f(mvv.w));
  *(short4*)&comb[(size_t)n * 1024 + c0] = ov;
}

// ---------------------------------------------------------------------------

extern "C" void kernel_launch(void* const* d_in, const int* in_sizes, int n_in,
                              void* d_out, int out_size, void* d_ws, size_t ws_size,
                              hipStream_t stream) {
  const float* x    = (const float*)d_in[0];
  const float* qkvw = (const float*)d_in[1];
  const float* qkvb = (const float*)d_in[2];
  const float* w1w  = (const float*)d_in[3];
  const float* w2w  = (const float*)d_in[4];
  const float* r1w  = (const float*)d_in[5];
  const float* r2w  = (const float*)d_in[6];
  const float* mvw  = (const float*)d_in[7];
  const float* mvb  = (const float*)d_in[8];
  const float* gw   = (const float*)d_in[9];
  const float* gb   = (const float*)d_in[10];
  const float* msc  = (const float*)d_in[11];
  const float* ow   = (const float*)d_in[12];
  const float* ob   = (const float*)d_in[13];
  const float* dlog = (const float*)d_in[14];
  const float* Jm   = (const float*)d_in[15];
  float* out = (float*)d_out;

  char* wsp = (char*)d_ws;
  auto alloc = [&](size_t bytes) {
    char* p = wsp;
    wsp += (bytes + 255) & ~(size_t)255;
    return p;
  };
  short* xb     = (short*)alloc((size_t)2048 * 1024 * 2);
  short* btall  = (short*)alloc((size_t)4480 * 1024 * 2);
  short* owT    = (short*)alloc((size_t)1024 * 1024 * 2);
  short* fusedC = (short*)alloc((size_t)2048 * 4480 * 2);
  float* projf  = (float*)alloc((size_t)2048 * 384 * 4);
  float* biasA  = (float*)alloc((size_t)4480 * 4);
  short* vtg    = (short*)alloc((size_t)32 * 64 * 1024 * 2);
  short* comb   = (short*)alloc((size_t)2048 * 1024 * 2);
  float* jwb    = (float*)alloc((size_t)32 * 6144 * 4);
  float* rlb    = (float*)alloc((size_t)32768 * 6 * 4);
  float* msb    = (float*)alloc((size_t)2048 * 16 * 4);
  float* Of     = (float*)alloc((size_t)1024 * 4096 * 4);
  float* Mlb    = (float*)alloc((size_t)1024 * 128 * 4);

  k_prep<<<8722, 256, 0, stream>>>(x, qkvw, mvw, ow, w1w, w2w, r1w, r2w, gw,
                                   qkvb, mvb, xb, btall, owT, biasA);

  k_gemmF<<<dim3(16, 35), 256, 0, stream>>>(xb, btall, fusedC, biasA, projf);

  k_vtr<<<dim3(32, 2, 32), dim3(32, 8), 0, stream>>>(fusedC, vtg);
  k_attn<<<1024, 256, 0, stream>>>(fusedC, vtg, Of, Mlb);

  k_lines<<<128, 256, 0, stream>>>(projf, Jm, jwb, rlb);
  k_mscore<<<8192, 256, 0, stream>>>(jwb, rlb, dlog, msb);
  k_combine<<<2048, 256, 0, stream>>>(Of, Mlb, fusedC, projf, msb, msc, gb, comb);

  k_gemm<64><<<dim3(32, 8), 256, 0, stream>>>(comb, owT, out, ob, 1024, 1024);
}

// Round 11
// 117.296 us; speedup vs baseline: 1.1898x; 1.0820x over previous
//
#include <hip/hip_runtime.h>
#include <hip/hip_bf16.h>
#include <stdint.h>

// ---------------------------------------------------------------------------
// TrigramWriteMemoryAttention  (B=2, T=1024, D=1024, H=16, dh=64, pd=4)
// Fused buffer layout (bf16, row stride 4480):
//   cols 0:1024 Q | 1024:2048 K | 2048:3072 V | 3072:4096 mem_val | 4096:4480 small
// small cols (also written f32 to projf[2048][384]):
//   0:64 xw1a | 64:128 xw1b | 128:192 w2 | 192:256 r1 | 256:320 r2 | 320:336 gate
// ---------------------------------------------------------------------------

typedef __attribute__((ext_vector_type(8))) __bf16 bf16v8;
typedef __attribute__((ext_vector_type(8))) short  s16x8;
typedef __attribute__((ext_vector_type(4))) float  f32x4;

#define LOG2E 1.4426950408889634f

__device__ __forceinline__ float bf2f(short s) {
  union { uint32_t u; float f; } cv; cv.u = ((uint32_t)(uint16_t)s) << 16; return cv.f;
}
__device__ __forceinline__ short f2bf(float f) {
  union { float f; uint32_t u; } cv; cv.f = f;
  uint32_t r = cv.u + 0x7fffu + ((cv.u >> 16) & 1u);
  return (short)(r >> 16);
}

__device__ __forceinline__ f32x4 mfma_bf16(s16x8 a, s16x8 b, f32x4 c) {
  return __builtin_amdgcn_mfma_f32_16x16x32_bf16(
      __builtin_bit_cast(bf16v8, a), __builtin_bit_cast(bf16v8, b), c, 0, 0, 0);
}

__device__ __forceinline__ void gload_lds16(const void* g, void* l) {
  __builtin_amdgcn_global_load_lds(
      (const __attribute__((address_space(1))) uint32_t*)g,
      (__attribute__((address_space(3))) uint32_t*)l, 16, 0, 0);
}

// ---------------- fused prep: cvt + 3x transposed weight conv + smallw + bias

__global__ __launch_bounds__(256) void k_prep(
    const float* __restrict__ x, const float* __restrict__ qkvw,
    const float* __restrict__ mvw, const float* __restrict__ ow,
    const float* __restrict__ w1w, const float* __restrict__ w2w,
    const float* __restrict__ r1w, const float* __restrict__ r2w,
    const float* __restrict__ gw, const float* __restrict__ qkvb,
    const float* __restrict__ mvb,
    short* __restrict__ xb, short* __restrict__ btall, short* __restrict__ owT,
    float* __restrict__ biasAll) {
  __shared__ float tile[32][33];
  const int bid = blockIdx.x;
  const int tid = threadIdx.x;
  if (bid < 2048) {  // cvt
    const int i = (bid * 256 + tid) * 4;
    float4 v = *(const float4*)&x[i];
    short4 o;
    o.x = f2bf(v.x); o.y = f2bf(v.y); o.z = f2bf(v.z); o.w = f2bf(v.w);
    *(short4*)&xb[i] = o;
    return;
  }
  if (bid < 7168) {  // transposed conversions
    const float* W; short* Wt; int N, u;
    if (bid < 5120)      { W = qkvw; Wt = btall;                       N = 3072; u = bid - 2048; }
    else if (bid < 6144) { W = mvw;  Wt = btall + (size_t)3072 * 1024; N = 1024; u = bid - 5120; }
    else                 { W = ow;   Wt = owT;                         N = 1024; u = bid - 6144; }
    const int ntiles = N >> 5;
    const int n0 = (u % ntiles) * 32, k0 = (u / ntiles) * 32;
    const int tx = tid & 31, ty = tid >> 5;  // 32x8
#pragma unroll
    for (int i = 0; i < 4; i++)
      tile[ty + i * 8][tx] = W[(size_t)(k0 + ty + i * 8) * N + n0 + tx];
    __syncthreads();
#pragma unroll
    for (int i = 0; i < 4; i++)
      Wt[(size_t)(n0 + ty + i * 8) * 1024 + k0 + tx] = f2bf(tile[tx][ty + i * 8]);
    return;
  }
  if (bid < 8704) {  // small weights
    const int idx = (bid - 7168) * 256 + tid;  // 384*1024
    const int r = idx >> 10, k = idx & 1023;
    float v = 0.f;
    if (r < 64)       v = w1w[(size_t)k * 64 + r];
    else if (r < 128) v = w1w[(size_t)(1024 + k) * 64 + (r - 64)];
    else if (r < 192) v = w2w[(size_t)k * 64 + (r - 128)];
    else if (r < 256) v = r1w[(size_t)k * 64 + (r - 192)];
    else if (r < 320) v = r2w[(size_t)k * 64 + (r - 256)];
    else if (r < 336) v = gw[(size_t)k * 16 + (r - 320)];
    btall[(size_t)4096 * 1024 + idx] = f2bf(v);
    return;
  }
  {  // bias
    const int i = (bid - 8704) * 256 + tid;
    if (i < 4480) {
      float v = 0.f;
      if (i < 3072) v = qkvb[i];
      else if (i < 4096) v = mvb[i - 3072];
      biasAll[i] = v;
    }
  }
}

// ---------------- fused projection GEMM (2-phase double-buffered) ----------

__global__ __launch_bounds__(256) void k_gemmF(const short* __restrict__ A,
                                               const short* __restrict__ Bt,
                                               short* __restrict__ C,
                                               const float* __restrict__ bias,
                                               float* __restrict__ projf) {
  const int N = 4480, K = 1024;
  __shared__ short As[2][128 * 32];
  __shared__ short Bs[2][128 * 32];
  const int m0 = blockIdx.x * 128, n0 = blockIdx.y * 128;
  const int tid = threadIdx.x;
  const int lane = tid & 63, w = tid >> 6;
  const int wr = (w >> 1) * 64, wc = (w & 1) * 64;
  const int l15 = lane & 15, lg = lane >> 4;
  const int r0e = tid >> 2, c0e = (tid & 3) << 3;
  const int r1e = (tid + 256) >> 2, c1e = ((tid + 256) & 3) << 3;
  f32x4 acc[4][4] = {};

  gload_lds16(A + (size_t)(m0 + r0e) * K + c0e, &As[0][tid * 8]);
  gload_lds16(A + (size_t)(m0 + r1e) * K + c1e, &As[0][(tid + 256) * 8]);
  gload_lds16(Bt + (size_t)(n0 + r0e) * K + c0e, &Bs[0][tid * 8]);
  gload_lds16(Bt + (size_t)(n0 + r1e) * K + c1e, &Bs[0][(tid + 256) * 8]);
  __syncthreads();

  const int nkt = K >> 5;
  for (int kt = 0; kt < nkt; kt++) {
    const int cur = kt & 1;
    if (kt + 1 < nkt) {
      const int k0n = (kt + 1) << 5;
      const int nxt = cur ^ 1;
      gload_lds16(A + (size_t)(m0 + r0e) * K + k0n + c0e, &As[nxt][tid * 8]);
      gload_lds16(A + (size_t)(m0 + r1e) * K + k0n + c1e, &As[nxt][(tid + 256) * 8]);
      gload_lds16(Bt + (size_t)(n0 + r0e) * K + k0n + c0e, &Bs[nxt][tid * 8]);
      gload_lds16(Bt + (size_t)(n0 + r1e) * K + k0n + c1e, &Bs[nxt][(tid + 256) * 8]);
    }
    s16x8 af[4], bfv[4];
#pragma unroll
    for (int i = 0; i < 4; i++) {
      af[i]  = *(const s16x8*)&As[cur][(wr + i * 16 + l15) * 32 + lg * 8];
      bfv[i] = *(const s16x8*)&Bs[cur][(wc + i * 16 + l15) * 32 + lg * 8];
    }
    __builtin_amdgcn_s_setprio(1);
#pragma unroll
    for (int mi = 0; mi < 4; mi++)
#pragma unroll
      for (int ni = 0; ni < 4; ni++)
        acc[mi][ni] = mfma_bf16(af[mi], bfv[ni], acc[mi][ni]);
    __builtin_amdgcn_s_setprio(0);
    __syncthreads();
  }
  const bool isproj = (n0 >= 4096);
#pragma unroll
  for (int mi = 0; mi < 4; mi++)
#pragma unroll
    for (int ni = 0; ni < 4; ni++) {
      const int col = n0 + wc + ni * 16 + l15;
      const float bv = bias[col];
#pragma unroll
      for (int r = 0; r < 4; r++) {
        const int row = m0 + wr + mi * 16 + lg * 4 + r;
        const float v = acc[mi][ni][r] + bv;
        if (isproj) projf[(size_t)row * 384 + (col - 4096)] = v;
        else        C[(size_t)row * 4480 + col] = f2bf(v);
      }
    }
}

// ---------------- generic GEMM (templated BM; BN=128; 2-phase dbuf) --------

template <int BM>
__global__ __launch_bounds__(256) void k_gemm(const short* __restrict__ A,
                                              const short* __restrict__ Bt,
                                              float* __restrict__ C,
                                              const float* __restrict__ bias,
                                              int N, int K) {
  constexpr int MI = BM / 32;
  __shared__ short As[2][BM * 32];
  __shared__ short Bs[2][128 * 32];
  const int m0 = blockIdx.x * BM, n0 = blockIdx.y * 128;
  const int tid = threadIdx.x;
  const int lane = tid & 63, w = tid >> 6;
  const int wr = (w >> 1) * (BM / 2), wc = (w & 1) * 64;
  const int l15 = lane & 15, lg = lane >> 4;
  const int r0e = tid >> 2, c0e = (tid & 3) << 3;
  const int r1e = (tid + 256) >> 2, c1e = ((tid + 256) & 3) << 3;
  f32x4 acc[MI][4] = {};

  auto stage = [&](int buf, int k0) {
    if constexpr (BM == 128) {
      gload_lds16(A + (size_t)(m0 + r0e) * K + k0 + c0e, &As[buf][tid * 8]);
      gload_lds16(A + (size_t)(m0 + r1e) * K + k0 + c1e, &As[buf][(tid + 256) * 8]);
    } else {
      gload_lds16(A + (size_t)(m0 + r0e) * K + k0 + c0e, &As[buf][tid * 8]);
    }
    gload_lds16(Bt + (size_t)(n0 + r0e) * K + k0 + c0e, &Bs[buf][tid * 8]);
    gload_lds16(Bt + (size_t)(n0 + r1e) * K + k0 + c1e, &Bs[buf][(tid + 256) * 8]);
  };

  stage(0, 0);
  __syncthreads();
  const int nkt = K >> 5;
  for (int kt = 0; kt < nkt; kt++) {
    const int cur = kt & 1;
    if (kt + 1 < nkt) stage(cur ^ 1, (kt + 1) << 5);
    s16x8 af[MI], bfv[4];
#pragma unroll
    for (int i = 0; i < MI; i++)
      af[i] = *(const s16x8*)&As[cur][(wr + i * 16 + l15) * 32 + lg * 8];
#pragma unroll
    for (int i = 0; i < 4; i++)
      bfv[i] = *(const s16x8*)&Bs[cur][(wc + i * 16 + l15) * 32 + lg * 8];
    __builtin_amdgcn_s_setprio(1);
#pragma unroll
    for (int mi = 0; mi < MI; mi++)
#pragma unroll
      for (int ni = 0; ni < 4; ni++)
        acc[mi][ni] = mfma_bf16(af[mi], bfv[ni], acc[mi][ni]);
    __builtin_amdgcn_s_setprio(0);
    __syncthreads();
  }
#pragma unroll
  for (int mi = 0; mi < MI; mi++)
#pragma unroll
    for (int ni = 0; ni < 4; ni++) {
      const int col = n0 + wc + ni * 16 + l15;
      const float bv = bias ? bias[col] : 0.f;
#pragma unroll
      for (int r = 0; r < 4; r++) {
        const int row = m0 + wr + mi * 16 + lg * 4 + r;
        C[(size_t)row * N + col] = acc[mi][ni][r] + bv;
      }
    }
}

// ---------------- V transpose: fused V cols -> vtg[bh][64][1024] ------------

__global__ void k_vtr(const short* __restrict__ fused, short* __restrict__ vtg) {
  __shared__ short tile[32][33];
  const int bh = blockIdx.z;
  const int b = bh >> 4, h = bh & 15;
  const int t0 = blockIdx.x * 32, d0 = blockIdx.y * 32;
  const int tx = threadIdx.x, ty = threadIdx.y;  // 32x8
#pragma unroll
  for (int i = 0; i < 4; i++)
    tile[ty + i * 8][tx] =
        fused[(size_t)(b * 1024 + t0 + ty + i * 8) * 4480 + 2048 + h * 64 + d0 + tx];
  __syncthreads();
#pragma unroll
  for (int i = 0; i < 4; i++)
    vtg[(size_t)(bh * 64 + d0 + ty + i * 8) * 1024 + t0 + tx] = tile[tx][ty + i * 8];
}

// ---------------- flash attention, kv-split 2-way ----------------

__global__ __launch_bounds__(256) void k_attn(const short* __restrict__ fused,
                                              const short* __restrict__ vtg,
                                              float* __restrict__ Of,
                                              float* __restrict__ Ml) {
  const int id = blockIdx.x;
  const int j = 15 - (id >> 6);
  const int rem = id & 63;
  const int sid = rem >> 5, bh = rem & 31;
  const int b = bh >> 4, h = bh & 15;
  const int tid = threadIdx.x, lane = tid & 63, w = tid >> 6;
  const int l15 = lane & 15, lg = lane >> 4;
  const int q0 = j * 64;
  const int nkv = j + 1;
  const int half = (nkv + 1) >> 1;
  const int lo = sid ? half : 0;
  const int hi = sid ? nkv : half;
  const int pidx = ((j * 32 + bh) << 1) | sid;

  __shared__ short Kl[64 * 72];
  __shared__ short Vt[64 * 72];
  __shared__ short Pl[4][16 * 72];
  const short* base = fused + (size_t)b * 1024 * 4480;
  const short* vbase = vtg + (size_t)bh * 64 * 1024;

  const int e0 = tid, e1 = tid + 256;
  const int r0e = e0 >> 3, c0e = (e0 & 7) << 3;
  const int r1e = e1 >> 3, c1e = (e1 & 7) << 3;

  s16x8 qf[2];
#pragma unroll
  for (int ks = 0; ks < 2; ks++)
    qf[ks] = *(const s16x8*)&base[(size_t)(q0 + w * 16 + l15) * 4480 +
                                  h * 64 + ks * 32 + lg * 8];

  f32x4 O[4] = {};
  float m_run[4], l_run[4];
#pragma unroll
  for (int r = 0; r < 4; r++) { m_run[r] = -1e30f; l_run[r] = 0.f; }

  if (lo < hi) {
    const int kv0 = lo * 64;
    s16x8 ka = *(const s16x8*)&base[(size_t)(kv0 + r0e) * 4480 + 1024 + h * 64 + c0e];
    s16x8 kb = *(const s16x8*)&base[(size_t)(kv0 + r1e) * 4480 + 1024 + h * 64 + c1e];
    s16x8 va = *(const s16x8*)&vbase[(size_t)r0e * 1024 + kv0 + c0e];
    s16x8 vb = *(const s16x8*)&vbase[(size_t)r1e * 1024 + kv0 + c1e];
    *(s16x8*)&Kl[r0e * 72 + c0e] = ka;
    *(s16x8*)&Kl[r1e * 72 + c1e] = kb;
    *(s16x8*)&Vt[r0e * 72 + c0e] = va;
    *(s16x8*)&Vt[r1e * 72 + c1e] = vb;
  }
  __syncthreads();

  for (int kt = lo; kt < hi; kt++) {
    const int kv0 = kt * 64;
    const bool pf = (kt + 1 < hi);
    s16x8 kn0, kn1, vn0, vn1;
    if (pf) {
      const int kvn = kv0 + 64;
      kn0 = *(const s16x8*)&base[(size_t)(kvn + r0e) * 4480 + 1024 + h * 64 + c0e];
      kn1 = *(const s16x8*)&base[(size_t)(kvn + r1e) * 4480 + 1024 + h * 64 + c1e];
      vn0 = *(const s16x8*)&vbase[(size_t)r0e * 1024 + kvn + c0e];
      vn1 = *(const s16x8*)&vbase[(size_t)r1e * 1024 + kvn + c1e];
    }

    // S = Q @ K^T
    f32x4 S[4] = {};
    __builtin_amdgcn_s_setprio(1);
#pragma unroll
    for (int sf = 0; sf < 4; sf++) {
      s16x8 kf0 = *(const s16x8*)&Kl[(sf * 16 + l15) * 72 + lg * 8];
      s16x8 kf1 = *(const s16x8*)&Kl[(sf * 16 + l15) * 72 + 32 + lg * 8];
      S[sf] = mfma_bf16(qf[0], kf0, S[sf]);
      S[sf] = mfma_bf16(qf[1], kf1, S[sf]);
    }
    __builtin_amdgcn_s_setprio(0);

    const bool diag = (kt == j);
    float sv[4][4];
#pragma unroll
    for (int sf = 0; sf < 4; sf++)
#pragma unroll
      for (int r = 0; r < 4; r++) {
        float vv = S[sf][r] * 0.125f;
        if (diag) {
          const int sg = kv0 + sf * 16 + l15;
          const int qg = q0 + w * 16 + lg * 4 + r;
          if (sg > qg) vv = -1e30f;
        }
        sv[sf][r] = vv;
      }
#pragma unroll
    for (int r = 0; r < 4; r++) {
      float pm = fmaxf(fmaxf(sv[0][r], sv[1][r]), fmaxf(sv[2][r], sv[3][r]));
      pm = fmaxf(pm, __shfl_xor(pm, 1, 64));
      pm = fmaxf(pm, __shfl_xor(pm, 2, 64));
      pm = fmaxf(pm, __shfl_xor(pm, 4, 64));
      pm = fmaxf(pm, __shfl_xor(pm, 8, 64));
      if (pm > m_run[r] + 8.f) {  // T13 defer-max
        const float fac = exp2f((m_run[r] - pm) * LOG2E);
        m_run[r] = pm;
        l_run[r] *= fac;
#pragma unroll
        for (int nf = 0; nf < 4; nf++) O[nf][r] *= fac;
      }
      float rs = 0.f;
#pragma unroll
      for (int sf = 0; sf < 4; sf++) {
        float p = (sv[sf][r] <= -1e29f) ? 0.f : exp2f((sv[sf][r] - m_run[r]) * LOG2E);
        rs += p;
        Pl[w][(lg * 4 + r) * 72 + sf * 16 + l15] = f2bf(p);
      }
      rs += __shfl_xor(rs, 1, 64);
      rs += __shfl_xor(rs, 2, 64);
      rs += __shfl_xor(rs, 4, 64);
      rs += __shfl_xor(rs, 8, 64);
      l_run[r] += rs;
    }

    // O += P @ V
    __builtin_amdgcn_s_setprio(1);
#pragma unroll
    for (int ks = 0; ks < 2; ks++) {
      s16x8 pfr = *(const s16x8*)&Pl[w][l15 * 72 + ks * 32 + lg * 8];
#pragma unroll
      for (int nf = 0; nf < 4; nf++) {
        s16x8 vf = *(const s16x8*)&Vt[(nf * 16 + l15) * 72 + ks * 32 + lg * 8];
        O[nf] = mfma_bf16(pfr, vf, O[nf]);
      }
    }
    __builtin_amdgcn_s_setprio(0);

    __syncthreads();
    if (pf) {
      *(s16x8*)&Kl[r0e * 72 + c0e] = kn0;
      *(s16x8*)&Kl[r1e * 72 + c1e] = kn1;
      *(s16x8*)&Vt[r0e * 72 + c0e] = vn0;
      *(s16x8*)&Vt[r1e * 72 + c1e] = vn1;
      __syncthreads();
    }
  }

  float* ob = Of + (size_t)pidx * 4096;
  float* mb = Ml + (size_t)pidx * 128;
#pragma unroll
  for (int r = 0; r < 4; r++) {
    const int rloc = w * 16 + lg * 4 + r;
#pragma unroll
    for (int nf = 0; nf < 4; nf++)
      ob[rloc * 64 + nf * 16 + l15] = O[nf][r];
    if (l15 == 0) {
      mb[rloc] = m_run[r];
      mb[64 + rloc] = l_run[r];
    }
  }
}

// ---------------- Plucker helpers ----------------

__device__ __forceinline__ void exterior6(const float p1[4], const float p2[4], float L[6]) {
  L[0] = p1[0] * p2[1] - p1[1] * p2[0];
  L[1] = p1[0] * p2[2] - p1[2] * p2[0];
  L[2] = p1[0] * p2[3] - p1[3] * p2[0];
  L[3] = p1[1] * p2[2] - p1[2] * p2[1];
  L[4] = p1[1] * p2[3] - p1[3] * p2[1];
  L[5] = p1[2] * p2[3] - p1[3] * p2[2];
  float n = sqrtf(L[0] * L[0] + L[1] * L[1] + L[2] * L[2] +
                  L[3] * L[3] + L[4] * L[4] + L[5] * L[5]);
  float inv = 1.f / fmaxf(n, 1e-12f);
#pragma unroll
  for (int j = 0; j < 6; j++) L[j] *= inv;
}

// ---------------- fused lines + decayed memory score (prefix scan) --------
// ms[t] = d^t * sum_{i<=j} fac * r_i r_j P_ij[t-1],
// P_ij[t] = prefix sum over s<=t of d^{-s} Jw_si Jw_sj   (21 channels).
// Grid 32 blocks (one per bh) x 1024 threads (thread = t = s).
// Lines computed in-register from projf; no jw/rl globals needed.

__global__ __launch_bounds__(1024) void k_mscan(const float* __restrict__ proj,
                                                const float* __restrict__ Jm,
                                                const float* __restrict__ dlog,
                                                float* __restrict__ ms) {
  const int bh = blockIdx.x;
  const int b = bh >> 4, h = bh & 15;
  const int t = threadIdx.x;
  const int lane = t & 63, wv = t >> 6;   // 16 waves
  const int n = b * 1024 + t;
  const float d = 1.f / (1.f + expf(-dlog[h]));
  const float l2d = log2f(d);

  float p1[4], p2[4], L[6], Jw[6], rl[6];
#pragma unroll
  for (int p = 0; p < 4; p++) {
    float a  = (t >= 2) ? proj[(size_t)(n - 2) * 384 + h * 4 + p] : 0.f;
    float bb = (t >= 1) ? proj[(size_t)(n - 1) * 384 + 64 + h * 4 + p] : 0.f;
    p1[p] = a + bb;
    p2[p] = proj[(size_t)n * 384 + 128 + h * 4 + p];
  }
  exterior6(p1, p2, L);
#pragma unroll
  for (int j = 0; j < 6; j++) {
    float s = 0.f;
#pragma unroll
    for (int i = 0; i < 6; i++) s += L[i] * Jm[i * 6 + j];
    Jw[j] = s;
  }
#pragma unroll
  for (int p = 0; p < 4; p++) {
    p1[p] = proj[(size_t)n * 384 + 192 + h * 4 + p];
    p2[p] = proj[(size_t)n * 384 + 256 + h * 4 + p];
  }
  exterior6(p1, p2, rl);

  // 21 upper-triangle channels, weighted d^{-t}  (d=0.99 -> max ~2.8e4, safe)
  const float ws = exp2f(-(float)t * l2d);
  float c[21], loc[21];
  {
    int k = 0;
#pragma unroll
    for (int i = 0; i < 6; i++)
#pragma unroll
      for (int j = i; j < 6; j++) {
        loc[k] = ws * Jw[i] * Jw[j];
        c[k] = loc[k];
        k++;
      }
  }
  // wave-level inclusive scan
#pragma unroll
  for (int off = 1; off < 64; off <<= 1) {
#pragma unroll
    for (int k = 0; k < 21; k++) {
      float u = __shfl_up(c[k], off, 64);
      if (lane >= off) c[k] += u;
    }
  }
  __shared__ float wsum[16][21];
  __shared__ float woff[16][21];
  if (lane == 63)
#pragma unroll
    for (int k = 0; k < 21; k++) wsum[wv][k] = c[k];
  __syncthreads();
  if (t < 21) {
    float run = 0.f;
    for (int w2 = 0; w2 < 16; w2++) { woff[w2][t] = run; run += wsum[w2][t]; }
  }
  __syncthreads();
  // exclusive prefix (s < t) + quadratic form
  float q = 0.f;
  {
    int k = 0;
#pragma unroll
    for (int i = 0; i < 6; i++)
#pragma unroll
      for (int j = i; j < 6; j++) {
        const float P = woff[wv][k] + (c[k] - loc[k]);
        q += (i == j ? 1.f : 2.f) * rl[i] * rl[j] * P;
        k++;
      }
  }
  ms[(size_t)n * 16 + h] = exp2f((float)t * l2d) * q;
}

// ---------------- combine (fused kv-split merge) ----------------

__global__ __launch_bounds__(256) void k_combine(const float* __restrict__ Of,
                                                 const float* __restrict__ Ml,
                                                 const short* __restrict__ fused,
                                                 const float* __restrict__ proj,
                                                 const float* __restrict__ ms,
                                                 const float* __restrict__ mem_scale,
                                                 const float* __restrict__ gate_b,
                                                 short* __restrict__ comb) {
  const int n = blockIdx.x;
  const int tid = threadIdx.x;
  __shared__ float gsh;
  if (tid < 16) {
    const float gp = proj[(size_t)n * 384 + 320 + tid] + gate_b[tid];
    const float g = 1.f / (1.f + expf(-gp));
    const float sc = ms[(size_t)n * 16 + tid] * mem_scale[tid];
    const float sg = 1.f / (1.f + expf(-sc));
    float v = sg * g;
    v += __shfl_xor(v, 1, 64);
    v += __shfl_xor(v, 2, 64);
    v += __shfl_xor(v, 4, 64);
    v += __shfl_xor(v, 8, 64);
    if (tid == 0) gsh = v * (1.f / 16.f);
  }
  __syncthreads();
  const float g = gsh;
  const int b = n >> 10, t = n & 1023;
  const int c0 = tid * 4;
  const int h = c0 >> 6, coff = c0 & 63;
  const int bh = b * 16 + h;
  const int p = ((t >> 6) * 32 + bh) << 1;
  const int rloc = t & 63;
  const float m0v = Ml[(size_t)p * 128 + rloc];
  const float l0v = Ml[(size_t)p * 128 + 64 + rloc];
  const float m1v = Ml[(size_t)(p + 1) * 128 + rloc];
  const float l1v = Ml[(size_t)(p + 1) * 128 + 64 + rloc];
  const float M = fmaxf(m0v, m1v);
  const float w0 = exp2f((m0v - M) * LOG2E);
  const float w1 = exp2f((m1v - M) * LOG2E);
  const float inv = 1.f / (w0 * l0v + w1 * l1v);
  f32x4 o0 = *(const f32x4*)&Of[(size_t)p * 4096 + rloc * 64 + coff];
  f32x4 o1 = *(const f32x4*)&Of[(size_t)(p + 1) * 4096 + rloc * 64 + coff];
  short4 mvv = *(const short4*)&fused[(size_t)n * 4480 + 3072 + c0];
  short4 ov;
  ov.x = f2bf((w0 * o0[0] + w1 * o1[0]) * inv + g * bf2f(mvv.x));
  ov.y = f2bf((w0 * o0[1] + w1 * o1[1]) * inv + g * bf2f(mvv.y));
  ov.z = f2bf((w0 * o0[2] + w1 * o1[2]) * inv + g * bf2f(mvv.z));
  ov.w = f2bf((w0 * o0[3] + w1 * o1[3]) * inv + g * bf2f(mvv.w));
  *(short4*)&comb[(size_t)n * 1024 + c0] = ov;
}

// ---------------------------------------------------------------------------

extern "C" void kernel_launch(void* const* d_in, const int* in_sizes, int n_in,
                              void* d_out, int out_size, void* d_ws, size_t ws_size,
                              hipStream_t stream) {
  const float* x    = (const float*)d_in[0];
  const float* qkvw = (const float*)d_in[1];
  const float* qkvb = (const float*)d_in[2];
  const float* w1w  = (const float*)d_in[3];
  const float* w2w  = (const float*)d_in[4];
  const float* r1w  = (const float*)d_in[5];
  const float* r2w  = (const float*)d_in[6];
  const float* mvw  = (const float*)d_in[7];
  const float* mvb  = (const float*)d_in[8];
  const float* gw   = (const float*)d_in[9];
  const float* gb   = (const float*)d_in[10];
  const float* msc  = (const float*)d_in[11];
  const float* ow   = (const float*)d_in[12];
  const float* ob   = (const float*)d_in[13];
  const float* dlog = (const float*)d_in[14];
  const float* Jm   = (const float*)d_in[15];
  float* out = (float*)d_out;

  char* wsp = (char*)d_ws;
  auto alloc = [&](size_t bytes) {
    char* p = wsp;
    wsp += (bytes + 255) & ~(size_t)255;
    return p;
  };
  short* xb     = (short*)alloc((size_t)2048 * 1024 * 2);
  short* btall  = (short*)alloc((size_t)4480 * 1024 * 2);
  short* owT    = (short*)alloc((size_t)1024 * 1024 * 2);
  short* fusedC = (short*)alloc((size_t)2048 * 4480 * 2);
  float* projf  = (float*)alloc((size_t)2048 * 384 * 4);
  float* biasA  = (float*)alloc((size_t)4480 * 4);
  short* vtg    = (short*)alloc((size_t)32 * 64 * 1024 * 2);
  short* comb   = (short*)alloc((size_t)2048 * 1024 * 2);
  float* msb    = (float*)alloc((size_t)2048 * 16 * 4);
  float* Of     = (float*)alloc((size_t)1024 * 4096 * 4);
  float* Mlb    = (float*)alloc((size_t)1024 * 128 * 4);

  k_prep<<<8722, 256, 0, stream>>>(x, qkvw, mvw, ow, w1w, w2w, r1w, r2w, gw,
                                   qkvb, mvb, xb, btall, owT, biasA);

  k_gemmF<<<dim3(16, 35), 256, 0, stream>>>(xb, btall, fusedC, biasA, projf);

  k_vtr<<<dim3(32, 2, 32), dim3(32, 8), 0, stream>>>(fusedC, vtg);
  k_attn<<<1024, 256, 0, stream>>>(fusedC, vtg, Of, Mlb);

  k_mscan<<<32, 1024, 0, stream>>>(projf, Jm, dlog, msb);
  k_combine<<<2048, 256, 0, stream>>>(Of, Mlb, fusedC, projf, msb, msc, gb, comb);

  k_gemm<64><<<dim3(32, 8), 256, 0, stream>>>(comb, owT, out, ob, 1024, 1024);
}

// Round 12
// 116.320 us; speedup vs baseline: 1.1998x; 1.0084x over previous
//
#include <hip/hip_runtime.h>
#include <hip/hip_bf16.h>
#include <stdint.h>

// ---------------------------------------------------------------------------
// TrigramWriteMemoryAttention  (B=2, T=1024, D=1024, H=16, dh=64, pd=4)
// Fused buffer layout (bf16, row stride 4480):
//   cols 0:1024 Q | 1024:2048 K | 2048:3072 V (not written; V goes transposed
//   to vtg from gemmF's epilogue) | 3072:4096 mem_val | 4096:4480 small
// small cols (also written f32 to projf[2048][384]):
//   0:64 xw1a | 64:128 xw1b | 128:192 w2 | 192:256 r1 | 256:320 r2 | 320:336 gate
// ---------------------------------------------------------------------------

typedef __attribute__((ext_vector_type(8))) __bf16 bf16v8;
typedef __attribute__((ext_vector_type(8))) short  s16x8;
typedef __attribute__((ext_vector_type(4))) float  f32x4;

#define LOG2E 1.4426950408889634f

__device__ __forceinline__ float bf2f(short s) {
  union { uint32_t u; float f; } cv; cv.u = ((uint32_t)(uint16_t)s) << 16; return cv.f;
}
__device__ __forceinline__ short f2bf(float f) {
  union { float f; uint32_t u; } cv; cv.f = f;
  uint32_t r = cv.u + 0x7fffu + ((cv.u >> 16) & 1u);
  return (short)(r >> 16);
}

__device__ __forceinline__ f32x4 mfma_bf16(s16x8 a, s16x8 b, f32x4 c) {
  return __builtin_amdgcn_mfma_f32_16x16x32_bf16(
      __builtin_bit_cast(bf16v8, a), __builtin_bit_cast(bf16v8, b), c, 0, 0, 0);
}

__device__ __forceinline__ void gload_lds16(const void* g, void* l) {
  __builtin_amdgcn_global_load_lds(
      (const __attribute__((address_space(1))) uint32_t*)g,
      (__attribute__((address_space(3))) uint32_t*)l, 16, 0, 0);
}

// ---------------- fused prep: cvt + 3x transposed weight conv + smallw + bias

__global__ __launch_bounds__(256) void k_prep(
    const float* __restrict__ x, const float* __restrict__ qkvw,
    const float* __restrict__ mvw, const float* __restrict__ ow,
    const float* __restrict__ w1w, const float* __restrict__ w2w,
    const float* __restrict__ r1w, const float* __restrict__ r2w,
    const float* __restrict__ gw, const float* __restrict__ qkvb,
    const float* __restrict__ mvb,
    short* __restrict__ xb, short* __restrict__ btall, short* __restrict__ owT,
    float* __restrict__ biasAll) {
  __shared__ float tile[32][33];
  const int bid = blockIdx.x;
  const int tid = threadIdx.x;
  if (bid < 2048) {  // cvt
    const int i = (bid * 256 + tid) * 4;
    float4 v = *(const float4*)&x[i];
    short4 o;
    o.x = f2bf(v.x); o.y = f2bf(v.y); o.z = f2bf(v.z); o.w = f2bf(v.w);
    *(short4*)&xb[i] = o;
    return;
  }
  if (bid < 7168) {  // transposed conversions
    const float* W; short* Wt; int N, u;
    if (bid < 5120)      { W = qkvw; Wt = btall;                       N = 3072; u = bid - 2048; }
    else if (bid < 6144) { W = mvw;  Wt = btall + (size_t)3072 * 1024; N = 1024; u = bid - 5120; }
    else                 { W = ow;   Wt = owT;                         N = 1024; u = bid - 6144; }
    const int ntiles = N >> 5;
    const int n0 = (u % ntiles) * 32, k0 = (u / ntiles) * 32;
    const int tx = tid & 31, ty = tid >> 5;  // 32x8
#pragma unroll
    for (int i = 0; i < 4; i++)
      tile[ty + i * 8][tx] = W[(size_t)(k0 + ty + i * 8) * N + n0 + tx];
    __syncthreads();
#pragma unroll
    for (int i = 0; i < 4; i++)
      Wt[(size_t)(n0 + ty + i * 8) * 1024 + k0 + tx] = f2bf(tile[tx][ty + i * 8]);
    return;
  }
  if (bid < 8704) {  // small weights
    const int idx = (bid - 7168) * 256 + tid;  // 384*1024
    const int r = idx >> 10, k = idx & 1023;
    float v = 0.f;
    if (r < 64)       v = w1w[(size_t)k * 64 + r];
    else if (r < 128) v = w1w[(size_t)(1024 + k) * 64 + (r - 64)];
    else if (r < 192) v = w2w[(size_t)k * 64 + (r - 128)];
    else if (r < 256) v = r1w[(size_t)k * 64 + (r - 192)];
    else if (r < 320) v = r2w[(size_t)k * 64 + (r - 256)];
    else if (r < 336) v = gw[(size_t)k * 16 + (r - 320)];
    btall[(size_t)4096 * 1024 + idx] = f2bf(v);
    return;
  }
  {  // bias
    const int i = (bid - 8704) * 256 + tid;
    if (i < 4480) {
      float v = 0.f;
      if (i < 3072) v = qkvb[i];
      else if (i < 4096) v = mvb[i - 3072];
      biasAll[i] = v;
    }
  }
}

// ---------------- fused projection GEMM (ring-4 panels, 1 barrier / 2) -----
// C[2048][4480] = xb @ btall^T + biasAll.
// proj cols (>=4096) -> projf f32; V cols [2048,3072) -> vtg TRANSPOSED via
// LDS round-trip (coalesced stores); others -> fusedC bf16.
// LDS pool: 4 ring panels A(8KB)+B(8KB) = 64KB; reused as the 128x136
// transpose buffer in the V-epilogue (after the final barrier).

__global__ __launch_bounds__(256) void k_gemmF(const short* __restrict__ A,
                                               const short* __restrict__ Bt,
                                               short* __restrict__ C,
                                               const float* __restrict__ bias,
                                               float* __restrict__ projf,
                                               short* __restrict__ vtg) {
  const int N = 4480, K = 1024;
  __shared__ short pool[32768];  // 64 KB
  short* Asp = pool;             // [4][4096]
  short* Bsp = pool + 16384;     // [4][4096]
  const int m0 = blockIdx.x * 128, n0 = blockIdx.y * 128;
  const int tid = threadIdx.x;
  const int lane = tid & 63, w = tid >> 6;
  const int wr = (w >> 1) * 64, wc = (w & 1) * 64;
  const int l15 = lane & 15, lg = lane >> 4;
  const int r0e = tid >> 2, c0e = (tid & 3) << 3;
  const int r1e = (tid + 256) >> 2, c1e = ((tid + 256) & 3) << 3;
  f32x4 acc[4][4] = {};

  auto stage = [&](int buf, int k0) {
    gload_lds16(A + (size_t)(m0 + r0e) * K + k0 + c0e, Asp + buf * 4096 + tid * 8);
    gload_lds16(A + (size_t)(m0 + r1e) * K + k0 + c1e, Asp + buf * 4096 + (tid + 256) * 8);
    gload_lds16(Bt + (size_t)(n0 + r0e) * K + k0 + c0e, Bsp + buf * 4096 + tid * 8);
    gload_lds16(Bt + (size_t)(n0 + r1e) * K + k0 + c1e, Bsp + buf * 4096 + (tid + 256) * 8);
  };

  stage(0, 0);
  stage(1, 32);
  __syncthreads();

  const int nkt = K >> 5;  // 32, even
  for (int kp = 0; kp < nkt; kp += 2) {
    if (kp + 2 < nkt) stage((kp + 2) & 3, (kp + 2) << 5);
    if (kp + 3 < nkt) stage((kp + 3) & 3, (kp + 3) << 5);
#pragma unroll
    for (int u = 0; u < 2; u++) {
      const int cur = (kp + u) & 3;
      s16x8 af[4], bfv[4];
#pragma unroll
      for (int i = 0; i < 4; i++) {
        af[i]  = *(const s16x8*)&Asp[cur * 4096 + (wr + i * 16 + l15) * 32 + lg * 8];
        bfv[i] = *(const s16x8*)&Bsp[cur * 4096 + (wc + i * 16 + l15) * 32 + lg * 8];
      }
      __builtin_amdgcn_s_setprio(1);
#pragma unroll
      for (int mi = 0; mi < 4; mi++)
#pragma unroll
        for (int ni = 0; ni < 4; ni++)
          acc[mi][ni] = mfma_bf16(af[mi], bfv[ni], acc[mi][ni]);
      __builtin_amdgcn_s_setprio(0);
    }
    __syncthreads();
  }

  const bool isproj = (n0 >= 4096);
  const bool isv = (n0 >= 2048) && (n0 < 3072);
  if (isv) {
    // transpose via LDS: T[col 128][row 136-pad], then coalesced vtg stores
    short* T = pool;  // 128*136*2 = 34816 B <= 64 KB (panels dead after loop)
#pragma unroll
    for (int mi = 0; mi < 4; mi++)
#pragma unroll
      for (int ni = 0; ni < 4; ni++) {
        const int colLoc = wc + ni * 16 + l15;
        const float bv = bias[n0 + colLoc];
#pragma unroll
        for (int r = 0; r < 4; r++)
          T[colLoc * 136 + wr + mi * 16 + lg * 4 + r] = f2bf(acc[mi][ni][r] + bv);
      }
    __syncthreads();
    const int b = m0 >> 10, t0 = m0 & 1023;
#pragma unroll
    for (int q = 0; q < 8; q++) {
      const int colLoc = w * 32 + q * 4 + (lane >> 4);
      const int chunk = lane & 15;
      s16x8 v = *(const s16x8*)&T[colLoc * 136 + chunk * 8];
      const int cd = n0 + colLoc - 2048;
      const int hh = cd >> 6, d = cd & 63;
      *(s16x8*)&vtg[((size_t)((b << 4) + hh) * 64 + d) * 1024 + t0 + chunk * 8] = v;
    }
    return;
  }
#pragma unroll
  for (int mi = 0; mi < 4; mi++)
#pragma unroll
    for (int ni = 0; ni < 4; ni++) {
      const int col = n0 + wc + ni * 16 + l15;
      const float bv = bias[col];
#pragma unroll
      for (int r = 0; r < 4; r++) {
        const int row = m0 + wr + mi * 16 + lg * 4 + r;
        const float v = acc[mi][ni][r] + bv;
        if (isproj) projf[(size_t)row * 384 + (col - 4096)] = v;
        else        C[(size_t)row * 4480 + col] = f2bf(v);
      }
    }
}

// ---------------- generic GEMM (templated BM; BN=128; ring-4 panels) -------

template <int BM>
__global__ __launch_bounds__(256) void k_gemm(const short* __restrict__ A,
                                              const short* __restrict__ Bt,
                                              float* __restrict__ C,
                                              const float* __restrict__ bias,
                                              int N, int K) {
  constexpr int MI = BM / 32;
  __shared__ short As[4][BM * 32];
  __shared__ short Bs[4][128 * 32];
  const int m0 = blockIdx.x * BM, n0 = blockIdx.y * 128;
  const int tid = threadIdx.x;
  const int lane = tid & 63, w = tid >> 6;
  const int wr = (w >> 1) * (BM / 2), wc = (w & 1) * 64;
  const int l15 = lane & 15, lg = lane >> 4;
  const int r0e = tid >> 2, c0e = (tid & 3) << 3;
  const int r1e = (tid + 256) >> 2, c1e = ((tid + 256) & 3) << 3;
  f32x4 acc[MI][4] = {};

  auto stage = [&](int buf, int k0) {
    if constexpr (BM == 128) {
      gload_lds16(A + (size_t)(m0 + r0e) * K + k0 + c0e, &As[buf][tid * 8]);
      gload_lds16(A + (size_t)(m0 + r1e) * K + k0 + c1e, &As[buf][(tid + 256) * 8]);
    } else {
      gload_lds16(A + (size_t)(m0 + r0e) * K + k0 + c0e, &As[buf][tid * 8]);
    }
    gload_lds16(Bt + (size_t)(n0 + r0e) * K + k0 + c0e, &Bs[buf][tid * 8]);
    gload_lds16(Bt + (size_t)(n0 + r1e) * K + k0 + c1e, &Bs[buf][(tid + 256) * 8]);
  };

  stage(0, 0);
  stage(1, 32);
  __syncthreads();
  const int nkt = K >> 5;  // even
  for (int kp = 0; kp < nkt; kp += 2) {
    if (kp + 2 < nkt) stage((kp + 2) & 3, (kp + 2) << 5);
    if (kp + 3 < nkt) stage((kp + 3) & 3, (kp + 3) << 5);
#pragma unroll
    for (int u = 0; u < 2; u++) {
      const int cur = (kp + u) & 3;
      s16x8 af[MI], bfv[4];
#pragma unroll
      for (int i = 0; i < MI; i++)
        af[i] = *(const s16x8*)&As[cur][(wr + i * 16 + l15) * 32 + lg * 8];
#pragma unroll
      for (int i = 0; i < 4; i++)
        bfv[i] = *(const s16x8*)&Bs[cur][(wc + i * 16 + l15) * 32 + lg * 8];
      __builtin_amdgcn_s_setprio(1);
#pragma unroll
      for (int mi = 0; mi < MI; mi++)
#pragma unroll
        for (int ni = 0; ni < 4; ni++)
          acc[mi][ni] = mfma_bf16(af[mi], bfv[ni], acc[mi][ni]);
      __builtin_amdgcn_s_setprio(0);
    }
    __syncthreads();
  }
#pragma unroll
  for (int mi = 0; mi < MI; mi++)
#pragma unroll
    for (int ni = 0; ni < 4; ni++) {
      const int col = n0 + wc + ni * 16 + l15;
      const float bv = bias ? bias[col] : 0.f;
#pragma unroll
      for (int r = 0; r < 4; r++) {
        const int row = m0 + wr + mi * 16 + lg * 4 + r;
        C[(size_t)row * N + col] = acc[mi][ni][r] + bv;
      }
    }
}

// ---------------- flash attention, kv-split 2-way ----------------

__global__ __launch_bounds__(256) void k_attn(const short* __restrict__ fused,
                                              const short* __restrict__ vtg,
                                              float* __restrict__ Of,
                                              float* __restrict__ Ml) {
  const int id = blockIdx.x;
  const int j = 15 - (id >> 6);
  const int rem = id & 63;
  const int sid = rem >> 5, bh = rem & 31;
  const int b = bh >> 4, h = bh & 15;
  const int tid = threadIdx.x, lane = tid & 63, w = tid >> 6;
  const int l15 = lane & 15, lg = lane >> 4;
  const int q0 = j * 64;
  const int nkv = j + 1;
  const int half = (nkv + 1) >> 1;
  const int lo = sid ? half : 0;
  const int hi = sid ? nkv : half;
  const int pidx = ((j * 32 + bh) << 1) | sid;

  __shared__ short Kl[64 * 72];
  __shared__ short Vt[64 * 72];
  __shared__ short Pl[4][16 * 72];
  const short* base = fused + (size_t)b * 1024 * 4480;
  const short* vbase = vtg + (size_t)bh * 64 * 1024;

  const int e0 = tid, e1 = tid + 256;
  const int r0e = e0 >> 3, c0e = (e0 & 7) << 3;
  const int r1e = e1 >> 3, c1e = (e1 & 7) << 3;

  s16x8 qf[2];
#pragma unroll
  for (int ks = 0; ks < 2; ks++)
    qf[ks] = *(const s16x8*)&base[(size_t)(q0 + w * 16 + l15) * 4480 +
                                  h * 64 + ks * 32 + lg * 8];

  f32x4 O[4] = {};
  float m_run[4], l_run[4];
#pragma unroll
  for (int r = 0; r < 4; r++) { m_run[r] = -1e30f; l_run[r] = 0.f; }

  if (lo < hi) {
    const int kv0 = lo * 64;
    s16x8 ka = *(const s16x8*)&base[(size_t)(kv0 + r0e) * 4480 + 1024 + h * 64 + c0e];
    s16x8 kb = *(const s16x8*)&base[(size_t)(kv0 + r1e) * 4480 + 1024 + h * 64 + c1e];
    s16x8 va = *(const s16x8*)&vbase[(size_t)r0e * 1024 + kv0 + c0e];
    s16x8 vb = *(const s16x8*)&vbase[(size_t)r1e * 1024 + kv0 + c1e];
    *(s16x8*)&Kl[r0e * 72 + c0e] = ka;
    *(s16x8*)&Kl[r1e * 72 + c1e] = kb;
    *(s16x8*)&Vt[r0e * 72 + c0e] = va;
    *(s16x8*)&Vt[r1e * 72 + c1e] = vb;
  }
  __syncthreads();

  for (int kt = lo; kt < hi; kt++) {
    const int kv0 = kt * 64;
    const bool pf = (kt + 1 < hi);
    s16x8 kn0, kn1, vn0, vn1;
    if (pf) {
      const int kvn = kv0 + 64;
      kn0 = *(const s16x8*)&base[(size_t)(kvn + r0e) * 4480 + 1024 + h * 64 + c0e];
      kn1 = *(const s16x8*)&base[(size_t)(kvn + r1e) * 4480 + 1024 + h * 64 + c1e];
      vn0 = *(const s16x8*)&vbase[(size_t)r0e * 1024 + kvn + c0e];
      vn1 = *(const s16x8*)&vbase[(size_t)r1e * 1024 + kvn + c1e];
    }

    // S = Q @ K^T
    f32x4 S[4] = {};
    __builtin_amdgcn_s_setprio(1);
#pragma unroll
    for (int sf = 0; sf < 4; sf++) {
      s16x8 kf0 = *(const s16x8*)&Kl[(sf * 16 + l15) * 72 + lg * 8];
      s16x8 kf1 = *(const s16x8*)&Kl[(sf * 16 + l15) * 72 + 32 + lg * 8];
      S[sf] = mfma_bf16(qf[0], kf0, S[sf]);
      S[sf] = mfma_bf16(qf[1], kf1, S[sf]);
    }
    __builtin_amdgcn_s_setprio(0);

    const bool diag = (kt == j);
    float sv[4][4];
#pragma unroll
    for (int sf = 0; sf < 4; sf++)
#pragma unroll
      for (int r = 0; r < 4; r++) {
        float vv = S[sf][r] * 0.125f;
        if (diag) {
          const int sg = kv0 + sf * 16 + l15;
          const int qg = q0 + w * 16 + lg * 4 + r;
          if (sg > qg) vv = -1e30f;
        }
        sv[sf][r] = vv;
      }
#pragma unroll
    for (int r = 0; r < 4; r++) {
      float pm = fmaxf(fmaxf(sv[0][r], sv[1][r]), fmaxf(sv[2][r], sv[3][r]));
      pm = fmaxf(pm, __shfl_xor(pm, 1, 64));
      pm = fmaxf(pm, __shfl_xor(pm, 2, 64));
      pm = fmaxf(pm, __shfl_xor(pm, 4, 64));
      pm = fmaxf(pm, __shfl_xor(pm, 8, 64));
      if (pm > m_run[r] + 8.f) {  // T13 defer-max
        const float fac = exp2f((m_run[r] - pm) * LOG2E);
        m_run[r] = pm;
        l_run[r] *= fac;
#pragma unroll
        for (int nf = 0; nf < 4; nf++) O[nf][r] *= fac;
      }
      float rs = 0.f;
#pragma unroll
      for (int sf = 0; sf < 4; sf++) {
        float p = (sv[sf][r] <= -1e29f) ? 0.f : exp2f((sv[sf][r] - m_run[r]) * LOG2E);
        rs += p;
        Pl[w][(lg * 4 + r) * 72 + sf * 16 + l15] = f2bf(p);
      }
      rs += __shfl_xor(rs, 1, 64);
      rs += __shfl_xor(rs, 2, 64);
      rs += __shfl_xor(rs, 4, 64);
      rs += __shfl_xor(rs, 8, 64);
      l_run[r] += rs;
    }

    // O += P @ V
    __builtin_amdgcn_s_setprio(1);
#pragma unroll
    for (int ks = 0; ks < 2; ks++) {
      s16x8 pfr = *(const s16x8*)&Pl[w][l15 * 72 + ks * 32 + lg * 8];
#pragma unroll
      for (int nf = 0; nf < 4; nf++) {
        s16x8 vf = *(const s16x8*)&Vt[(nf * 16 + l15) * 72 + ks * 32 + lg * 8];
        O[nf] = mfma_bf16(pfr, vf, O[nf]);
      }
    }
    __builtin_amdgcn_s_setprio(0);

    __syncthreads();
    if (pf) {
      *(s16x8*)&Kl[r0e * 72 + c0e] = kn0;
      *(s16x8*)&Kl[r1e * 72 + c1e] = kn1;
      *(s16x8*)&Vt[r0e * 72 + c0e] = vn0;
      *(s16x8*)&Vt[r1e * 72 + c1e] = vn1;
      __syncthreads();
    }
  }

  float* ob = Of + (size_t)pidx * 4096;
  float* mb = Ml + (size_t)pidx * 128;
#pragma unroll
  for (int r = 0; r < 4; r++) {
    const int rloc = w * 16 + lg * 4 + r;
#pragma unroll
    for (int nf = 0; nf < 4; nf++)
      ob[rloc * 64 + nf * 16 + l15] = O[nf][r];
    if (l15 == 0) {
      mb[rloc] = m_run[r];
      mb[64 + rloc] = l_run[r];
    }
  }
}

// ---------------- Plucker helpers ----------------

__device__ __forceinline__ void exterior6(const float p1[4], const float p2[4], float L[6]) {
  L[0] = p1[0] * p2[1] - p1[1] * p2[0];
  L[1] = p1[0] * p2[2] - p1[2] * p2[0];
  L[2] = p1[0] * p2[3] - p1[3] * p2[0];
  L[3] = p1[1] * p2[2] - p1[2] * p2[1];
  L[4] = p1[1] * p2[3] - p1[3] * p2[1];
  L[5] = p1[2] * p2[3] - p1[3] * p2[2];
  float n = sqrtf(L[0] * L[0] + L[1] * L[1] + L[2] * L[2] +
                  L[3] * L[3] + L[4] * L[4] + L[5] * L[5]);
  float inv = 1.f / fmaxf(n, 1e-12f);
#pragma unroll
  for (int j = 0; j < 6; j++) L[j] *= inv;
}

// ---------------- fused lines + decayed memory score (prefix scan) --------

__global__ __launch_bounds__(1024) void k_mscan(const float* __restrict__ proj,
                                                const float* __restrict__ Jm,
                                                const float* __restrict__ dlog,
                                                float* __restrict__ ms) {
  const int bh = blockIdx.x;
  const int b = bh >> 4, h = bh & 15;
  const int t = threadIdx.x;
  const int lane = t & 63, wv = t >> 6;   // 16 waves
  const int n = b * 1024 + t;
  const float d = 1.f / (1.f + expf(-dlog[h]));
  const float l2d = log2f(d);

  float p1[4], p2[4], L[6], Jw[6], rl[6];
#pragma unroll
  for (int p = 0; p < 4; p++) {
    float a  = (t >= 2) ? proj[(size_t)(n - 2) * 384 + h * 4 + p] : 0.f;
    float bb = (t >= 1) ? proj[(size_t)(n - 1) * 384 + 64 + h * 4 + p] : 0.f;
    p1[p] = a + bb;
    p2[p] = proj[(size_t)n * 384 + 128 + h * 4 + p];
  }
  exterior6(p1, p2, L);
#pragma unroll
  for (int j = 0; j < 6; j++) {
    float s = 0.f;
#pragma unroll
    for (int i = 0; i < 6; i++) s += L[i] * Jm[i * 6 + j];
    Jw[j] = s;
  }
#pragma unroll
  for (int p = 0; p < 4; p++) {
    p1[p] = proj[(size_t)n * 384 + 192 + h * 4 + p];
    p2[p] = proj[(size_t)n * 384 + 256 + h * 4 + p];
  }
  exterior6(p1, p2, rl);

  const float ws = exp2f(-(float)t * l2d);
  float c[21], loc[21];
  {
    int k = 0;
#pragma unroll
    for (int i = 0; i < 6; i++)
#pragma unroll
      for (int j = i; j < 6; j++) {
        loc[k] = ws * Jw[i] * Jw[j];
        c[k] = loc[k];
        k++;
      }
  }
#pragma unroll
  for (int off = 1; off < 64; off <<= 1) {
#pragma unroll
    for (int k = 0; k < 21; k++) {
      float u = __shfl_up(c[k], off, 64);
      if (lane >= off) c[k] += u;
    }
  }
  __shared__ float wsum[16][21];
  __shared__ float woff[16][21];
  if (lane == 63)
#pragma unroll
    for (int k = 0; k < 21; k++) wsum[wv][k] = c[k];
  __syncthreads();
  if (t < 21) {
    float run = 0.f;
    for (int w2 = 0; w2 < 16; w2++) { woff[w2][t] = run; run += wsum[w2][t]; }
  }
  __syncthreads();
  float q = 0.f;
  {
    int k = 0;
#pragma unroll
    for (int i = 0; i < 6; i++)
#pragma unroll
      for (int j = i; j < 6; j++) {
        const float P = woff[wv][k] + (c[k] - loc[k]);
        q += (i == j ? 1.f : 2.f) * rl[i] * rl[j] * P;
        k++;
      }
  }
  ms[(size_t)n * 16 + h] = exp2f((float)t * l2d) * q;
}

// ---------------- combine (fused kv-split merge) ----------------

__global__ __launch_bounds__(256) void k_combine(const float* __restrict__ Of,
                                                 const float* __restrict__ Ml,
                                                 const short* __restrict__ fused,
                                                 const float* __restrict__ proj,
                                                 const float* __restrict__ ms,
                                                 const float* __restrict__ mem_scale,
                                                 const float* __restrict__ gate_b,
                                                 short* __restrict__ comb) {
  const int n = blockIdx.x;
  const int tid = threadIdx.x;
  __shared__ float gsh;
  if (tid < 16) {
    const float gp = proj[(size_t)n * 384 + 320 + tid] + gate_b[tid];
    const float g = 1.f / (1.f + expf(-gp));
    const float sc = ms[(size_t)n * 16 + tid] * mem_scale[tid];
    const float sg = 1.f / (1.f + expf(-sc));
    float v = sg * g;
    v += __shfl_xor(v, 1, 64);
    v += __shfl_xor(v, 2, 64);
    v += __shfl_xor(v, 4, 64);
    v += __shfl_xor(v, 8, 64);
    if (tid == 0) gsh = v * (1.f / 16.f);
  }
  __syncthreads();
  const float g = gsh;
  const int b = n >> 10, t = n & 1023;
  const int c0 = tid * 4;
  const int h = c0 >> 6, coff = c0 & 63;
  const int bh = b * 16 + h;
  const int p = ((t >> 6) * 32 + bh) << 1;
  const int rloc = t & 63;
  const float m0v = Ml[(size_t)p * 128 + rloc];
  const float l0v = Ml[(size_t)p * 128 + 64 + rloc];
  const float m1v = Ml[(size_t)(p + 1) * 128 + rloc];
  const float l1v = Ml[(size_t)(p + 1) * 128 + 64 + rloc];
  const float M = fmaxf(m0v, m1v);
  const float w0 = exp2f((m0v - M) * LOG2E);
  const float w1 = exp2f((m1v - M) * LOG2E);
  const float inv = 1.f / (w0 * l0v + w1 * l1v);
  f32x4 o0 = *(const f32x4*)&Of[(size_t)p * 4096 + rloc * 64 + coff];
  f32x4 o1 = *(const f32x4*)&Of[(size_t)(p + 1) * 4096 + rloc * 64 + coff];
  short4 mvv = *(const short4*)&fused[(size_t)n * 4480 + 3072 + c0];
  short4 ov;
  ov.x = f2bf((w0 * o0[0] + w1 * o1[0]) * inv + g * bf2f(mvv.x));
  ov.y = f2bf((w0 * o0[1] + w1 * o1[1]) * inv + g * bf2f(mvv.y));
  ov.z = f2bf((w0 * o0[2] + w1 * o1[2]) * inv + g * bf2f(mvv.z));
  ov.w = f2bf((w0 * o0[3] + w1 * o1[3]) * inv + g * bf2f(mvv.w));
  *(short4*)&comb[(size_t)n * 1024 + c0] = ov;
}

// ---------------------------------------------------------------------------

extern "C" void kernel_launch(void* const* d_in, const int* in_sizes, int n_in,
                              void* d_out, int out_size, void* d_ws, size_t ws_size,
                              hipStream_t stream) {
  const float* x    = (const float*)d_in[0];
  const float* qkvw = (const float*)d_in[1];
  const float* qkvb = (const float*)d_in[2];
  const float* w1w  = (const float*)d_in[3];
  const float* w2w  = (const float*)d_in[4];
  const float* r1w  = (const float*)d_in[5];
  const float* r2w  = (const float*)d_in[6];
  const float* mvw  = (const float*)d_in[7];
  const float* mvb  = (const float*)d_in[8];
  const float* gw   = (const float*)d_in[9];
  const float* gb   = (const float*)d_in[10];
  const float* msc  = (const float*)d_in[11];
  const float* ow   = (const float*)d_in[12];
  const float* ob   = (const float*)d_in[13];
  const float* dlog = (const float*)d_in[14];
  const float* Jm   = (const float*)d_in[15];
  float* out = (float*)d_out;

  char* wsp = (char*)d_ws;
  auto alloc = [&](size_t bytes) {
    char* p = wsp;
    wsp += (bytes + 255) & ~(size_t)255;
    return p;
  };
  short* xb     = (short*)alloc((size_t)2048 * 1024 * 2);
  short* btall  = (short*)alloc((size_t)4480 * 1024 * 2);
  short* owT    = (short*)alloc((size_t)1024 * 1024 * 2);
  short* fusedC = (short*)alloc((size_t)2048 * 4480 * 2);
  float* projf  = (float*)alloc((size_t)2048 * 384 * 4);
  float* biasA  = (float*)alloc((size_t)4480 * 4);
  short* vtg    = (short*)alloc((size_t)32 * 64 * 1024 * 2);
  short* comb   = (short*)alloc((size_t)2048 * 1024 * 2);
  float* msb    = (float*)alloc((size_t)2048 * 16 * 4);
  float* Of     = (float*)alloc((size_t)1024 * 4096 * 4);
  float* Mlb    = (float*)alloc((size_t)1024 * 128 * 4);

  k_prep<<<8722, 256, 0, stream>>>(x, qkvw, mvw, ow, w1w, w2w, r1w, r2w, gw,
                                   qkvb, mvb, xb, btall, owT, biasA);

  k_gemmF<<<dim3(16, 35), 256, 0, stream>>>(xb, btall, fusedC, biasA, projf, vtg);

  k_attn<<<1024, 256, 0, stream>>>(fusedC, vtg, Of, Mlb);

  k_mscan<<<32, 1024, 0, stream>>>(projf, Jm, dlog, msb);
  k_combine<<<2048, 256, 0, stream>>>(Of, Mlb, fusedC, projf, msb, msc, gb, comb);

  k_gemm<64><<<dim3(32, 8), 256, 0, stream>>>(comb, owT, out, ob, 1024, 1024);
}